// Round 4
// baseline (778.328 us; speedup 1.0000x reference)
//
#include <hip/hip_runtime.h>
#include <math.h>

#define DIM 384
#define NUM_HEADS 8
#define RES 14
#define RES2 7
#define NPOS 196
#define N2 49
#define DHEAD 64
#define NH_KD 128
#define DH 512
#define OUT_DIM 768
#define BATCH 512
#define SCALE_Q 0.25f

typedef unsigned short u16;
typedef short s16x8 __attribute__((ext_vector_type(8)));
typedef short s16x4 __attribute__((ext_vector_type(4)));
typedef float f32x4 __attribute__((ext_vector_type(4)));
typedef unsigned int u32x2 __attribute__((ext_vector_type(2)));

__device__ __forceinline__ float bf2f(u16 u) {
  union { unsigned int i; float f; } v; v.i = ((unsigned int)u) << 16; return v.f;
}
__device__ __forceinline__ u16 f2bf(float f) {
  union { unsigned int i; float f; } v; v.f = f;
  unsigned int r = v.i + 0x7fffu + ((v.i >> 16) & 1u);
  return (u16)(r >> 16);
}

// ---------- small prep kernels ----------
__global__ __launch_bounds__(256) void k_f2bf(const float* __restrict__ s, u16* __restrict__ d, int n) {
  int i = blockIdx.x * 256 + threadIdx.x;
  if (i < n) d[i] = f2bf(s[i]);
}

// bias permuted to MFMA fragment order: bxp[h][m][ncol][16], entry f = bias(h, m, n=f*16+ncol), 0 if n>=196
__global__ __launch_bounds__(256) void k_biasx_p(const float* __restrict__ ab, const int* __restrict__ idxs,
                                                 float* __restrict__ bxp, int noff) {
  int i = blockIdx.x * 256 + threadIdx.x;
  if (i >= NUM_HEADS * N2 * 16 * 16) return;
  int f = i & 15, c = (i >> 4) & 15;
  int m = (i >> 8) % N2, h = i / (N2 * 256);
  int n = f * 16 + c;
  bxp[i] = (n < NPOS) ? ab[h * noff + idxs[m * NPOS + n]] : 0.f;
}

// ---------- x (f32 [b][384][196]) -> xbT (bf16 [b][196][384]) ----------
__global__ __launch_bounds__(256) void k_transpose(const float* __restrict__ x, u16* __restrict__ xt) {
  int b = blockIdx.y, c0 = blockIdx.x * 64;
  __shared__ u16 tile[64][196];
  int tid = threadIdx.x, wave = tid >> 6, lane = tid & 63;
  const float* xb = x + (size_t)b * DIM * NPOS;
  for (int r = wave; r < 64; r += 4) {
    const float* row = xb + (size_t)(c0 + r) * NPOS;
    tile[r][lane]       = f2bf(row[lane]);
    tile[r][lane + 64]  = f2bf(row[lane + 64]);
    tile[r][lane + 128] = f2bf(row[lane + 128]);
    if (lane < 4) tile[r][lane + 192] = f2bf(row[lane + 192]);
  }
  __syncthreads();
  u16* xtb = xt + (size_t)b * NPOS * DIM;
  for (int n = wave; n < NPOS; n += 4)
    xtb[(size_t)n * DIM + c0 + lane] = tile[lane][n];
}

// ---------- ql = dwconv_s2(x) + b + x[::2,::2]  -> qlT (bf16 [b][49][384]) ----------
__global__ __launch_bounds__(256) void k_dwconv_q(const u16* __restrict__ xt, const float* __restrict__ w,
                                                  const float* __restrict__ bias, u16* __restrict__ qlt) {
  int b = blockIdx.y;
  int lid = blockIdx.x * 256 + threadIdx.x;
  if (lid >= N2 * DIM) return;
  int n2 = lid / DIM, c = lid % DIM;
  int r = n2 / RES2, s = n2 % RES2;
  const u16* xb = xt + (size_t)b * NPOS * DIM;
  float acc = bias[c];
#pragma unroll
  for (int dy = 0; dy < 3; dy++) {
    int ry = 2 * r - 1 + dy;
    if (ry < 0 || ry >= RES) continue;
#pragma unroll
    for (int dx = 0; dx < 3; dx++) {
      int sx = 2 * s - 1 + dx;
      if (sx < 0 || sx >= RES) continue;
      acc += w[c * 9 + dy * 3 + dx] * bf2f(xb[(size_t)(ry * RES + sx) * DIM + c]);
    }
  }
  acc += bf2f(xb[(size_t)(2 * r * RES + 2 * s) * DIM + c]);  // strided residual
  qlt[((size_t)b * N2 + n2) * DIM + c] = f2bf(acc);
}

// ---------- generic  C[b][m][n] = (sum_k Arow[m][k]*Brow[n][k]) * s[ch] + (cb[ch]*s[ch]+t[ch]) ----------
// LDK=40 u16 (80 B = 5x16B): bank start = 20*row mod 32 -> 8 distinct 4-dword windows per
// 8 rows -> max 2-way aliasing on b128 frag reads (free), vs 8-way at stride 32.
// MFR: m-frags per wave (m-tile = MFR*64 rows).
template <int NFRAG, int MFR, bool CHAN_M, bool F32OUT>
__global__ __launch_bounds__(256) void k_gemm_bt(
    const u16* __restrict__ A, const u16* __restrict__ B, void* __restrict__ C,
    const float* __restrict__ cb, const float* __restrict__ bns, const float* __restrict__ bnt,
    long sAb, long sBb, long sCb, int K, int Marows, int Brows, int Mstore, int Nstore, int ldc) {
  constexpr int MROWS = MFR * 64;
  constexpr int LDK = 40;
  int b = blockIdx.y, m0 = blockIdx.x * MROWS;
  const u16* Ab = A + (size_t)b * sAb;
  const u16* Bb = B + (size_t)b * sBb;
  __shared__ __align__(16) u16 a_lds[MROWS * LDK];
  __shared__ __align__(16) u16 b_lds[NFRAG * 16 * LDK];
  int tid = threadIdx.x, w = tid >> 6, l = tid & 63;
  f32x4 acc[NFRAG * MFR];
#pragma unroll
  for (int i = 0; i < NFRAG * MFR; i++) acc[i] = (f32x4){0.f, 0.f, 0.f, 0.f};

  int brow0 = tid >> 2, bkoff = (tid & 3) * 8;

  for (int kk = 0; kk < K; kk += 32) {
    // --- stage A: MFR parts of 8 u16 per thread ---
#pragma unroll
    for (int j = 0; j < MFR; j++) {
      int p = tid * MFR + j;
      int row = p >> 2, part = p & 3;
      int rg = m0 + row; if (rg > Marows - 1) rg = Marows - 1;
      *(s16x8*)(&a_lds[row * LDK + part * 8]) = *(const s16x8*)(Ab + (size_t)rg * K + kk + part * 8);
    }
    // --- stage B ---
#pragma unroll
    for (int i = 0; i < (NFRAG + 3) / 4; i++) {
      int rb = i * 64 + brow0;
      if (rb < Brows)
        *(s16x8*)(&b_lds[rb * LDK + bkoff]) = *(const s16x8*)(Bb + (size_t)rb * K + kk + bkoff);
    }
    __syncthreads();
    s16x8 af[MFR];
#pragma unroll
    for (int mf = 0; mf < MFR; mf++)
      af[mf] = *(const s16x8*)(&a_lds[(w * 16 * MFR + mf * 16 + (l & 15)) * LDK + (l >> 4) * 8]);
#pragma unroll
    for (int f = 0; f < NFRAG; f++) {
      s16x8 bf = *(const s16x8*)(&b_lds[(f * 16 + (l & 15)) * LDK + (l >> 4) * 8]);
#pragma unroll
      for (int mf = 0; mf < MFR; mf++)
        acc[f * MFR + mf] = __builtin_amdgcn_mfma_f32_16x16x32_bf16(af[mf], bf, acc[f * MFR + mf], 0, 0, 0);
    }
    __syncthreads();
  }
  int ncol0 = l & 15;
#pragma unroll
  for (int f = 0; f < NFRAG; f++) {
    int n = f * 16 + ncol0;
#pragma unroll
    for (int mf = 0; mf < MFR; mf++) {
      int mbase = m0 + w * 16 * MFR + mf * 16 + (l >> 4) * 4;
#pragma unroll
      for (int r = 0; r < 4; r++) {
        int m = mbase + r;
        if (m < Mstore && n < Nstore) {
          int ch = CHAN_M ? m : n;
          float val = acc[f * MFR + mf][r] * bns[ch] + (cb[ch] * bns[ch] + bnt[ch]);
          size_t o = (size_t)b * sCb + (size_t)m * ldc + n;
          if (F32OUT) ((float*)C)[o] = val;
          else ((u16*)C)[o] = f2bf(val);
        }
      }
    }
  }
}

// ---------- v_local = BN(dwconv_s2(v4) + b) -> vlT (bf16 [b][49][512]) ----------
__global__ __launch_bounds__(256) void k_dwconv_v(const u16* __restrict__ v4, const float* __restrict__ w,
    const float* __restrict__ bias, const float* __restrict__ bns, const float* __restrict__ bnt,
    u16* __restrict__ vlt) {
  int b = blockIdx.y, ct = blockIdx.x;
  __shared__ u16 tile[64][196];
  int tid = threadIdx.x, wave = tid >> 6, lane = tid & 63;
  const u16* vbp = v4 + ((size_t)b * DH + ct * 64) * NPOS;
  for (int r = wave; r < 64; r += 4) {
    const u16* row = vbp + (size_t)r * NPOS;
    tile[r][lane]       = row[lane];
    tile[r][lane + 64]  = row[lane + 64];
    tile[r][lane + 128] = row[lane + 128];
    if (lane < 4) tile[r][lane + 192] = row[lane + 192];
  }
  __syncthreads();
  for (int idx = tid; idx < 64 * N2; idx += 256) {
    int cl = idx & 63, n2 = idx >> 6;
    int ch = ct * 64 + cl;
    int r = n2 / RES2, s = n2 % RES2;
    float acc = bias[ch];
#pragma unroll
    for (int dy = 0; dy < 3; dy++) {
      int ry = 2 * r - 1 + dy;
      if (ry < 0 || ry >= RES) continue;
#pragma unroll
      for (int dx = 0; dx < 3; dx++) {
        int sx = 2 * s - 1 + dx;
        if (sx < 0 || sx >= RES) continue;
        acc += w[ch * 9 + dy * 3 + dx] * bf2f(tile[cl][ry * RES + sx]);
      }
    }
    vlt[((size_t)b * N2 + n2) * DH + ch] = f2bf(acc * bns[ch] + bnt[ch]);
  }
}

// ---------- MFMA attention per (b,h) ----------
// P/V LDS rows stride 232 u16 = 116 dw; 116 mod 32 = 20 -> 8 distinct bank classes -> 2-way (free).
// o_lds (f32, stride 68) overlaps the dead q/k region: 49*68*4 = 13.3 KB < 17.4 KB.
__global__ __launch_bounds__(256) void k_attn_mfma(const u16* __restrict__ qT, const u16* __restrict__ kT,
    const u16* __restrict__ v4, const float* __restrict__ bxp, const u16* __restrict__ vlT,
    u16* __restrict__ gT) {
  int h = blockIdx.x, b = blockIdx.y;
  __shared__ __align__(16) u16 smem[64 * 32 + 208 * 32 + 64 * 232 + 64 * 232];
  u16* q_lds = smem;                       // 64*32
  u16* k_lds = smem + 64 * 32;             // 208*32
  u16* p_lds = smem + 64 * 32 + 208 * 32;  // 64*232
  u16* v_lds = p_lds + 64 * 232;           // 64*232
  float* o_lds = (float*)smem;             // overlaps q_lds+k_lds
  int tid = threadIdx.x, w = tid >> 6, l = tid & 63;

  // --- stage q: row = tid>>2, part = tid&3 (parts 2,3 = K-pad zeros) ---
  {
    int row = tid >> 2, part = tid & 3;
    s16x8 val = (s16x8){0, 0, 0, 0, 0, 0, 0, 0};
    if (part < 2 && row < N2)
      val = *(const s16x8*)(qT + ((size_t)b * N2 + row) * NH_KD + h * 16 + part * 8);
    *(s16x8*)(&q_lds[row * 32 + part * 8]) = val;
  }
  // --- stage k ---
  for (int row = tid >> 2; row < 208; row += 64) {
    int part = tid & 3;
    s16x8 val = (s16x8){0, 0, 0, 0, 0, 0, 0, 0};
    if (part < 2 && row < NPOS)
      val = *(const s16x8*)(kT + ((size_t)b * NPOS + row) * NH_KD + h * 16 + part * 8);
    *(s16x8*)(&k_lds[row * 32 + part * 8]) = val;
  }
  // --- stage v: wave w rows w*16..w*16+15; one 8B load per lane per row (49*8B = full 392B row) ---
  for (int r = 0; r < 16; r++) {
    int row = w * 16 + r;
    const u32x2* gsrc = (const u32x2*)(v4 + ((size_t)b * DH + h * DHEAD + row) * NPOS);
    u32x2* dst = (u32x2*)&v_lds[row * 232];
    if (l < 49)       dst[l] = gsrc[l];
    else if (l < 56)  dst[49 + (l - 49)] = (u32x2){0, 0};   // dw 98..111 zero
  }
  // --- zero p_lds cols 208..223 (dwords 104..111) ---
  for (int idx = tid; idx < 64 * 8; idx += 256)
    ((uint*)&p_lds[(idx >> 3) * 232])[104 + (idx & 7)] = 0;

  // --- bias fragment loads (issued before barrier; independent of LDS) ---
  int mbase = w * 16 + (l >> 4) * 4;
  int ncol = l & 15;
  f32x4 bq[4][4];
#pragma unroll
  for (int r = 0; r < 4; r++) {
    int mm = mbase + r; if (mm > N2 - 1) mm = N2 - 1;
    const float* bb = bxp + (((size_t)h * N2 + mm) * 16 + ncol) * 16;
#pragma unroll
    for (int q = 0; q < 4; q++) bq[r][q] = *(const f32x4*)(bb + q * 4);
  }
  __syncthreads();

  // --- QK^T: wave w owns rows w*16..w*16+15; 13 col-frags ---
  f32x4 s[13];
  {
    s16x8 af = *(const s16x8*)(&q_lds[(w * 16 + (l & 15)) * 32 + (l >> 4) * 8]);
#pragma unroll
    for (int f = 0; f < 13; f++) {
      s16x8 bf = *(const s16x8*)(&k_lds[(f * 16 + (l & 15)) * 32 + (l >> 4) * 8]);
      s[f] = __builtin_amdgcn_mfma_f32_16x16x32_bf16(af, bf, (f32x4){0.f, 0.f, 0.f, 0.f}, 0, 0, 0);
    }
  }
  // --- scale + bias + mask (C layout: col = l&15, row = (l>>4)*4 + reg) ---
#pragma unroll
  for (int f = 0; f < 13; f++) {
    int n = f * 16 + ncol;
#pragma unroll
    for (int r = 0; r < 4; r++) {
      int m = mbase + r;
      s[f][r] = (m < N2 && n < NPOS) ? s[f][r] * SCALE_Q + bq[r][f >> 2][f & 3] : -1e30f;
    }
  }
  // --- softmax: rows live in 16-lane groups -> shfl_xor 1,2,4,8 ---
#pragma unroll
  for (int r = 0; r < 4; r++) {
    float mx = s[0][r];
#pragma unroll
    for (int f = 1; f < 13; f++) mx = fmaxf(mx, s[f][r]);
    mx = fmaxf(mx, __shfl_xor(mx, 1)); mx = fmaxf(mx, __shfl_xor(mx, 2));
    mx = fmaxf(mx, __shfl_xor(mx, 4)); mx = fmaxf(mx, __shfl_xor(mx, 8));
    float sum = 0.f;
#pragma unroll
    for (int f = 0; f < 13; f++) { s[f][r] = __expf(s[f][r] - mx); sum += s[f][r]; }
    sum += __shfl_xor(sum, 1); sum += __shfl_xor(sum, 2);
    sum += __shfl_xor(sum, 4); sum += __shfl_xor(sum, 8);
    float inv = 1.f / sum;
#pragma unroll
    for (int f = 0; f < 13; f++) s[f][r] *= inv;
  }
  // --- P -> LDS (bf16), wave-local rows ---
#pragma unroll
  for (int f = 0; f < 13; f++) {
    int n = f * 16 + ncol;
#pragma unroll
    for (int r = 0; r < 4; r++)
      p_lds[(mbase + r) * 232 + n] = f2bf(s[f][r]);
  }
  __syncthreads();

  // --- PV: A = P rows (wave-local m-tile), B = V rows (d), K = 224 ---
  f32x4 o[4];
#pragma unroll
  for (int f = 0; f < 4; f++) o[f] = (f32x4){0.f, 0.f, 0.f, 0.f};
  for (int kk = 0; kk < 224; kk += 32) {
    s16x8 pa = *(const s16x8*)(&p_lds[(w * 16 + (l & 15)) * 232 + kk + (l >> 4) * 8]);
#pragma unroll
    for (int f = 0; f < 4; f++) {
      s16x8 vb = *(const s16x8*)(&v_lds[(f * 16 + (l & 15)) * 232 + kk + (l >> 4) * 8]);
      o[f] = __builtin_amdgcn_mfma_f32_16x16x32_bf16(pa, vb, o[f], 0, 0, 0);
    }
  }
  // --- o -> o_lds (overlaps dead q/k region; q/k reads all completed before prior barrier) ---
#pragma unroll
  for (int f = 0; f < 4; f++)
#pragma unroll
    for (int r = 0; r < 4; r++) {
      int m = mbase + r;
      if (m < N2) o_lds[m * 68 + f * 16 + ncol] = o[f][r];
    }
  __syncthreads();

  // --- cooperative epilogue: coalesced vlT add + gelu + gT store ---
  for (int idx = tid; idx < N2 * 16; idx += 256) {
    int row = idx >> 4, c4 = (idx & 15) << 2;
    f32x4 ov = *(const f32x4*)(&o_lds[row * 68 + c4]);
    size_t go = ((size_t)b * N2 + row) * DH + h * DHEAD + c4;
    s16x4 vv = *(const s16x4*)(vlT + go);
    s16x4 outv;
#pragma unroll
    for (int e = 0; e < 4; e++) {
      float xv = ov[e] + bf2f((u16)vv[e]);
      float g = 0.5f * xv * (1.f + erff(xv * 0.70710678118f));
      outv[e] = (short)f2bf(g);
    }
    *(s16x4*)(gT + go) = outv;
  }
}

extern "C" void kernel_launch(void* const* d_in, const int* in_sizes, int n_in,
                              void* d_out, int out_size, void* d_ws, size_t ws_size,
                              hipStream_t stream) {
  const float* x   = (const float*)d_in[0];
  const float* qlw = (const float*)d_in[1];
  const float* qlb = (const float*)d_in[2];
  const float* qpw = (const float*)d_in[3];
  const float* qpb = (const float*)d_in[4];
  const float* qbs = (const float*)d_in[5];
  const float* qbt = (const float*)d_in[6];
  const float* kw  = (const float*)d_in[7];
  const float* kb  = (const float*)d_in[8];
  const float* kbs = (const float*)d_in[9];
  const float* kbt = (const float*)d_in[10];
  const float* vw  = (const float*)d_in[11];
  const float* vb  = (const float*)d_in[12];
  const float* vbs = (const float*)d_in[13];
  const float* vbt = (const float*)d_in[14];
  const float* vlw = (const float*)d_in[15];
  const float* vlb = (const float*)d_in[16];
  const float* vls = (const float*)d_in[17];
  const float* vlt_in = (const float*)d_in[18];
  const float* pw  = (const float*)d_in[19];
  const float* pb  = (const float*)d_in[20];
  const float* pbs = (const float*)d_in[21];
  const float* pbt = (const float*)d_in[22];
  const float* ab  = (const float*)d_in[23];
  const int*   bidx = (const int*)d_in[24];
  int noff = in_sizes[23] / NUM_HEADS;

  char* ws = (char*)d_ws;
  size_t off = 0;
  auto alloc = [&](size_t bytes) { char* p = ws + off; off += (bytes + 255) & ~(size_t)255; return p; };
  u16* xbT = (u16*)alloc((size_t)BATCH * NPOS * DIM * 2);      // 77.1 MB (aliased by gT later)
  u16* kTm = (u16*)alloc((size_t)BATCH * NPOS * NH_KD * 2);    // 25.7 MB
  u16* qlT = (u16*)alloc((size_t)BATCH * N2 * DIM * 2);        // 19.3 MB
  u16* qTm = (u16*)alloc((size_t)BATCH * N2 * NH_KD * 2);      //  6.4 MB
  u16* v4m = (u16*)alloc((size_t)BATCH * DH * NPOS * 2);       // 102.8 MB
  u16* vlTm = (u16*)alloc((size_t)BATCH * N2 * DH * 2);        // 25.7 MB
  float* bxp = (float*)alloc((size_t)NUM_HEADS * N2 * 16 * 16 * 4);  // 0.8 MB
  u16* kwb = (u16*)alloc((size_t)NH_KD * DIM * 2);
  u16* vwb = (u16*)alloc((size_t)DH * DIM * 2);
  u16* qwb = (u16*)alloc((size_t)NH_KD * DIM * 2);
  u16* pwb = (u16*)alloc((size_t)OUT_DIM * DH * 2);
  u16* gTm = xbT;  // alias: all xbT readers complete before k_attn writes gT

  k_f2bf<<<(NH_KD * DIM + 255) / 256, 256, 0, stream>>>(kw, kwb, NH_KD * DIM);
  k_f2bf<<<(DH * DIM + 255) / 256, 256, 0, stream>>>(vw, vwb, DH * DIM);
  k_f2bf<<<(NH_KD * DIM + 255) / 256, 256, 0, stream>>>(qpw, qwb, NH_KD * DIM);
  k_f2bf<<<(OUT_DIM * DH + 255) / 256, 256, 0, stream>>>(pw, pwb, OUT_DIM * DH);
  k_biasx_p<<<(NUM_HEADS * N2 * 16 * 16 + 255) / 256, 256, 0, stream>>>(ab, bidx, bxp, noff);

  k_transpose<<<dim3(6, BATCH), 256, 0, stream>>>(x, xbT);
  k_dwconv_q<<<dim3((N2 * DIM + 255) / 256, BATCH), 256, 0, stream>>>(xbT, qlw, qlb, qlT);

  // k: C[b][n][o]  (m = n_spatial, ch = col), 128-row m-tile
  k_gemm_bt<8, 2, false, false><<<dim3(2, BATCH), 256, 0, stream>>>(
      xbT, kwb, kTm, kb, kbs, kbt,
      (long)NPOS * DIM, 0, (long)NPOS * NH_KD, DIM, NPOS, NH_KD, NPOS, NH_KD, NH_KD);
  // v: C[b][o][n]  (m = channel), 128-row m-tile
  k_gemm_bt<13, 2, true, false><<<dim3(4, BATCH), 256, 0, stream>>>(
      vwb, xbT, v4m, vb, vbs, vbt,
      0, (long)NPOS * DIM, (long)DH * NPOS, DIM, DH, NPOS, DH, NPOS, NPOS);
  // q: C[b][n2][o]
  k_gemm_bt<8, 1, false, false><<<dim3(1, BATCH), 256, 0, stream>>>(
      qlT, qwb, qTm, qpb, qbs, qbt,
      (long)N2 * DIM, 0, (long)N2 * NH_KD, DIM, N2, NH_KD, N2, NH_KD, NH_KD);

  k_dwconv_v<<<dim3(8, BATCH), 256, 0, stream>>>(v4m, vlw, vlb, vls, vlt_in, vlTm);
  k_attn_mfma<<<dim3(NUM_HEADS, BATCH), 256, 0, stream>>>(qTm, kTm, v4m, bxp, vlTm, gTm);

  // p: C[b][o][n2] -> d_out f32, 128-row m-tile
  k_gemm_bt<4, 2, true, true><<<dim3(6, BATCH), 256, 0, stream>>>(
      pwb, gTm, d_out, pb, pbs, pbt,
      0, (long)N2 * DH, (long)OUT_DIM * N2, DH, OUT_DIM, N2, OUT_DIM, N2, N2);
}

// Round 5
// 725.869 us; speedup vs baseline: 1.0723x; 1.0723x over previous
//
#include <hip/hip_runtime.h>
#include <math.h>

#define DIM 384
#define NUM_HEADS 8
#define RES 14
#define RES2 7
#define NPOS 196
#define N2 49
#define DHEAD 64
#define NH_KD 128
#define DH 512
#define OUT_DIM 768
#define BATCH 512
#define SCALE_Q 0.25f

typedef unsigned short u16;
typedef short s16x8 __attribute__((ext_vector_type(8)));
typedef short s16x4 __attribute__((ext_vector_type(4)));
typedef float f32x4 __attribute__((ext_vector_type(4)));
typedef unsigned int u32x2 __attribute__((ext_vector_type(2)));

__device__ __forceinline__ float bf2f(u16 u) {
  union { unsigned int i; float f; } v; v.i = ((unsigned int)u) << 16; return v.f;
}
__device__ __forceinline__ u16 f2bf(float f) {
  union { unsigned int i; float f; } v; v.f = f;
  unsigned int r = v.i + 0x7fffu + ((v.i >> 16) & 1u);
  return (u16)(r >> 16);
}

// ---------- small prep kernels ----------
__global__ __launch_bounds__(256) void k_f2bf(const float* __restrict__ s, u16* __restrict__ d, int n) {
  int i = blockIdx.x * 256 + threadIdx.x;
  if (i < n) d[i] = f2bf(s[i]);
}

// bias permuted to MFMA fragment order: bxp[h][m][ncol][16], entry f = bias(h, m, n=f*16+ncol), 0 if n>=196
__global__ __launch_bounds__(256) void k_biasx_p(const float* __restrict__ ab, const int* __restrict__ idxs,
                                                 float* __restrict__ bxp, int noff) {
  int i = blockIdx.x * 256 + threadIdx.x;
  if (i >= NUM_HEADS * N2 * 16 * 16) return;
  int f = i & 15, c = (i >> 4) & 15;
  int m = (i >> 8) % N2, h = i / (N2 * 256);
  int n = f * 16 + c;
  bxp[i] = (n < NPOS) ? ab[h * noff + idxs[m * NPOS + n]] : 0.f;
}

// ---------- x (f32 [b][384][196]) -> xbT (bf16 [b][196][384]) ----------
__global__ __launch_bounds__(256) void k_transpose(const float* __restrict__ x, u16* __restrict__ xt) {
  int b = blockIdx.y, c0 = blockIdx.x * 64;
  __shared__ u16 tile[64][196];
  int tid = threadIdx.x, wave = tid >> 6, lane = tid & 63;
  const float* xb = x + (size_t)b * DIM * NPOS;
  for (int r = wave; r < 64; r += 4) {
    const float* row = xb + (size_t)(c0 + r) * NPOS;
    tile[r][lane]       = f2bf(row[lane]);
    tile[r][lane + 64]  = f2bf(row[lane + 64]);
    tile[r][lane + 128] = f2bf(row[lane + 128]);
    if (lane < 4) tile[r][lane + 192] = f2bf(row[lane + 192]);
  }
  __syncthreads();
  u16* xtb = xt + (size_t)b * NPOS * DIM;
  for (int n = wave; n < NPOS; n += 4)
    xtb[(size_t)n * DIM + c0 + lane] = tile[lane][n];
}

// ---------- ql = dwconv_s2(x) + b + x[::2,::2]  -> qlT (bf16 [b][49][384]) ----------
__global__ __launch_bounds__(256) void k_dwconv_q(const u16* __restrict__ xt, const float* __restrict__ w,
                                                  const float* __restrict__ bias, u16* __restrict__ qlt) {
  int b = blockIdx.y;
  int lid = blockIdx.x * 256 + threadIdx.x;
  if (lid >= N2 * DIM) return;
  int n2 = lid / DIM, c = lid % DIM;
  int r = n2 / RES2, s = n2 % RES2;
  const u16* xb = xt + (size_t)b * NPOS * DIM;
  float acc = bias[c];
#pragma unroll
  for (int dy = 0; dy < 3; dy++) {
    int ry = 2 * r - 1 + dy;
    if (ry < 0 || ry >= RES) continue;
#pragma unroll
    for (int dx = 0; dx < 3; dx++) {
      int sx = 2 * s - 1 + dx;
      if (sx < 0 || sx >= RES) continue;
      acc += w[c * 9 + dy * 3 + dx] * bf2f(xb[(size_t)(ry * RES + sx) * DIM + c]);
    }
  }
  acc += bf2f(xb[(size_t)(2 * r * RES + 2 * s) * DIM + c]);  // strided residual
  qlt[((size_t)b * N2 + n2) * DIM + c] = f2bf(acc);
}

// ---------- generic  C[b][m][n] = (sum_k Arow[m][k]*Brow[n][k]) * s[ch] + (cb[ch]*s[ch]+t[ch]) ----------
// Dense LDK=32 rows + XOR granule swizzle: 16B granule g of row r stored at g^((r>>1)&3).
// Writes: per-row permutation keeps 256-dword coverage dense -> conflict-free.
// Reads: 16 lanes (rows r..r+15, fixed g) hit 8 distinct 4-dword windows -> 2-way (free, m136).
// Waves split the n-frags (f = w + 4*nf), share all 4 m-frags: 8 b128 reads / 16 MFMAs per K-step.
template <int NFRAG, bool CHAN_M, bool F32OUT>
__global__ __launch_bounds__(256) void k_gemm_bt(
    const u16* __restrict__ A, const u16* __restrict__ B, void* __restrict__ C,
    const float* __restrict__ cb, const float* __restrict__ bns, const float* __restrict__ bnt,
    long sAb, long sBb, long sCb, int K, int Marows, int Brows, int Mstore, int Nstore, int ldc) {
  constexpr int NBR = (NFRAG + 3) / 4;
  int b = blockIdx.y, m0 = blockIdx.x * 64;
  const u16* Ab = A + (size_t)b * sAb;
  const u16* Bb = B + (size_t)b * sBb;
  __shared__ __align__(16) u16 a_lds[64 * 32];
  __shared__ __align__(16) u16 b_lds[NFRAG * 16 * 32];
  int tid = threadIdx.x, w = tid >> 6, l = tid & 63;
  f32x4 acc[4][NBR];
#pragma unroll
  for (int mf = 0; mf < 4; mf++)
#pragma unroll
    for (int nf = 0; nf < NBR; nf++) acc[mf][nf] = (f32x4){0.f, 0.f, 0.f, 0.f};

  int srow = tid >> 2, sg = tid & 3;
  int ssw = sg ^ ((srow >> 1) & 3);              // swizzled write granule (row periodic-16: i*64 preserves)
  int arow_g = m0 + srow; if (arow_g > Marows - 1) arow_g = Marows - 1;
  int rrow = l & 15;
  int rg = (l >> 4) ^ ((rrow >> 1) & 3);         // swizzled read granule

  for (int kk = 0; kk < K; kk += 32) {
    *(s16x8*)(&a_lds[srow * 32 + ssw * 8]) = *(const s16x8*)(Ab + (size_t)arow_g * K + kk + sg * 8);
#pragma unroll
    for (int i = 0; i < NBR; i++) {
      int rb = i * 64 + srow;
      if (rb < Brows)
        *(s16x8*)(&b_lds[rb * 32 + ssw * 8]) = *(const s16x8*)(Bb + (size_t)rb * K + kk + sg * 8);
    }
    __syncthreads();
    s16x8 af[4];
#pragma unroll
    for (int mf = 0; mf < 4; mf++)
      af[mf] = *(const s16x8*)(&a_lds[(mf * 16 + rrow) * 32 + rg * 8]);
#pragma unroll
    for (int nf = 0; nf < NBR; nf++) {
      int f = w + nf * 4;
      if (f < NFRAG) {
        s16x8 bf = *(const s16x8*)(&b_lds[(f * 16 + rrow) * 32 + rg * 8]);
#pragma unroll
        for (int mf = 0; mf < 4; mf++)
          acc[mf][nf] = __builtin_amdgcn_mfma_f32_16x16x32_bf16(af[mf], bf, acc[mf][nf], 0, 0, 0);
      }
    }
    __syncthreads();
  }
  int ncolr = l & 15, mq = (l >> 4) * 4;
#pragma unroll
  for (int nf = 0; nf < NBR; nf++) {
    int f = w + nf * 4;
    if (f >= NFRAG) continue;
    int n = f * 16 + ncolr;
#pragma unroll
    for (int mf = 0; mf < 4; mf++) {
#pragma unroll
      for (int r = 0; r < 4; r++) {
        int m = m0 + mf * 16 + mq + r;
        if (m < Mstore && n < Nstore) {
          int ch = CHAN_M ? m : n;
          float val = acc[mf][nf][r] * bns[ch] + (cb[ch] * bns[ch] + bnt[ch]);
          size_t o = (size_t)b * sCb + (size_t)m * ldc + n;
          if (F32OUT) ((float*)C)[o] = val;
          else ((u16*)C)[o] = f2bf(val);
        }
      }
    }
  }
}

// ---------- v_local = BN(dwconv_s2(v4) + b) -> vlT (bf16 [b][49][512]) ----------
__global__ __launch_bounds__(256) void k_dwconv_v(const u16* __restrict__ v4, const float* __restrict__ w,
    const float* __restrict__ bias, const float* __restrict__ bns, const float* __restrict__ bnt,
    u16* __restrict__ vlt) {
  int b = blockIdx.y, ct = blockIdx.x;
  __shared__ u16 tile[64][196];
  int tid = threadIdx.x, wave = tid >> 6, lane = tid & 63;
  const u16* vbp = v4 + ((size_t)b * DH + ct * 64) * NPOS;
  for (int r = wave; r < 64; r += 4) {
    const u16* row = vbp + (size_t)r * NPOS;
    tile[r][lane]       = row[lane];
    tile[r][lane + 64]  = row[lane + 64];
    tile[r][lane + 128] = row[lane + 128];
    if (lane < 4) tile[r][lane + 192] = row[lane + 192];
  }
  __syncthreads();
  for (int idx = tid; idx < 64 * N2; idx += 256) {
    int cl = idx & 63, n2 = idx >> 6;
    int ch = ct * 64 + cl;
    int r = n2 / RES2, s = n2 % RES2;
    float acc = bias[ch];
#pragma unroll
    for (int dy = 0; dy < 3; dy++) {
      int ry = 2 * r - 1 + dy;
      if (ry < 0 || ry >= RES) continue;
#pragma unroll
      for (int dx = 0; dx < 3; dx++) {
        int sx = 2 * s - 1 + dx;
        if (sx < 0 || sx >= RES) continue;
        acc += w[ch * 9 + dy * 3 + dx] * bf2f(tile[cl][ry * RES + sx]);
      }
    }
    vlt[((size_t)b * N2 + n2) * DH + ch] = f2bf(acc * bns[ch] + bnt[ch]);
  }
}

// ---------- MFMA attention per (b,h) ----------
// P/V LDS rows stride 232 u16 = 116 dw; 116 mod 32 = 20 -> 8 distinct bank classes -> 2-way (free).
// o_lds (f32, stride 68) overlaps the dead q/k region: 49*68*4 = 13.3 KB < 17.4 KB.
__global__ __launch_bounds__(256) void k_attn_mfma(const u16* __restrict__ qT, const u16* __restrict__ kT,
    const u16* __restrict__ v4, const float* __restrict__ bxp, const u16* __restrict__ vlT,
    u16* __restrict__ gT) {
  int h = blockIdx.x, b = blockIdx.y;
  __shared__ __align__(16) u16 smem[64 * 32 + 208 * 32 + 64 * 232 + 64 * 232];
  u16* q_lds = smem;                       // 64*32
  u16* k_lds = smem + 64 * 32;             // 208*32
  u16* p_lds = smem + 64 * 32 + 208 * 32;  // 64*232
  u16* v_lds = p_lds + 64 * 232;           // 64*232
  float* o_lds = (float*)smem;             // overlaps q_lds+k_lds
  int tid = threadIdx.x, w = tid >> 6, l = tid & 63;

  // --- stage q: row = tid>>2, part = tid&3 (parts 2,3 = K-pad zeros) ---
  {
    int row = tid >> 2, part = tid & 3;
    s16x8 val = (s16x8){0, 0, 0, 0, 0, 0, 0, 0};
    if (part < 2 && row < N2)
      val = *(const s16x8*)(qT + ((size_t)b * N2 + row) * NH_KD + h * 16 + part * 8);
    *(s16x8*)(&q_lds[row * 32 + part * 8]) = val;
  }
  // --- stage k ---
  for (int row = tid >> 2; row < 208; row += 64) {
    int part = tid & 3;
    s16x8 val = (s16x8){0, 0, 0, 0, 0, 0, 0, 0};
    if (part < 2 && row < NPOS)
      val = *(const s16x8*)(kT + ((size_t)b * NPOS + row) * NH_KD + h * 16 + part * 8);
    *(s16x8*)(&k_lds[row * 32 + part * 8]) = val;
  }
  // --- stage v: wave w rows w*16..w*16+15; one 8B load per lane per row (49*8B = full 392B row) ---
  for (int r = 0; r < 16; r++) {
    int row = w * 16 + r;
    const u32x2* gsrc = (const u32x2*)(v4 + ((size_t)b * DH + h * DHEAD + row) * NPOS);
    u32x2* dst = (u32x2*)&v_lds[row * 232];
    if (l < 49)       dst[l] = gsrc[l];
    else if (l < 56)  dst[49 + (l - 49)] = (u32x2){0, 0};   // dw 98..111 zero
  }
  // --- zero p_lds cols 208..223 (dwords 104..111) ---
  for (int idx = tid; idx < 64 * 8; idx += 256)
    ((uint*)&p_lds[(idx >> 3) * 232])[104 + (idx & 7)] = 0;

  // --- bias fragment loads (issued before barrier; independent of LDS) ---
  int mbase = w * 16 + (l >> 4) * 4;
  int ncol = l & 15;
  f32x4 bq[4][4];
#pragma unroll
  for (int r = 0; r < 4; r++) {
    int mm = mbase + r; if (mm > N2 - 1) mm = N2 - 1;
    const float* bb = bxp + (((size_t)h * N2 + mm) * 16 + ncol) * 16;
#pragma unroll
    for (int q = 0; q < 4; q++) bq[r][q] = *(const f32x4*)(bb + q * 4);
  }
  __syncthreads();

  // --- QK^T: wave w owns rows w*16..w*16+15; 13 col-frags ---
  f32x4 s[13];
  {
    s16x8 af = *(const s16x8*)(&q_lds[(w * 16 + (l & 15)) * 32 + (l >> 4) * 8]);
#pragma unroll
    for (int f = 0; f < 13; f++) {
      s16x8 bf = *(const s16x8*)(&k_lds[(f * 16 + (l & 15)) * 32 + (l >> 4) * 8]);
      s[f] = __builtin_amdgcn_mfma_f32_16x16x32_bf16(af, bf, (f32x4){0.f, 0.f, 0.f, 0.f}, 0, 0, 0);
    }
  }
  // --- scale + bias + mask (C layout: col = l&15, row = (l>>4)*4 + reg) ---
#pragma unroll
  for (int f = 0; f < 13; f++) {
    int n = f * 16 + ncol;
#pragma unroll
    for (int r = 0; r < 4; r++) {
      int m = mbase + r;
      s[f][r] = (m < N2 && n < NPOS) ? s[f][r] * SCALE_Q + bq[r][f >> 2][f & 3] : -1e30f;
    }
  }
  // --- softmax: rows live in 16-lane groups -> shfl_xor 1,2,4,8 ---
#pragma unroll
  for (int r = 0; r < 4; r++) {
    float mx = s[0][r];
#pragma unroll
    for (int f = 1; f < 13; f++) mx = fmaxf(mx, s[f][r]);
    mx = fmaxf(mx, __shfl_xor(mx, 1)); mx = fmaxf(mx, __shfl_xor(mx, 2));
    mx = fmaxf(mx, __shfl_xor(mx, 4)); mx = fmaxf(mx, __shfl_xor(mx, 8));
    float sum = 0.f;
#pragma unroll
    for (int f = 0; f < 13; f++) { s[f][r] = __expf(s[f][r] - mx); sum += s[f][r]; }
    sum += __shfl_xor(sum, 1); sum += __shfl_xor(sum, 2);
    sum += __shfl_xor(sum, 4); sum += __shfl_xor(sum, 8);
    float inv = 1.f / sum;
#pragma unroll
    for (int f = 0; f < 13; f++) s[f][r] *= inv;
  }
  // --- P -> LDS (bf16), wave-local rows ---
#pragma unroll
  for (int f = 0; f < 13; f++) {
    int n = f * 16 + ncol;
#pragma unroll
    for (int r = 0; r < 4; r++)
      p_lds[(mbase + r) * 232 + n] = f2bf(s[f][r]);
  }
  __syncthreads();

  // --- PV: A = P rows (wave-local m-tile), B = V rows (d), K = 224 ---
  f32x4 o[4];
#pragma unroll
  for (int f = 0; f < 4; f++) o[f] = (f32x4){0.f, 0.f, 0.f, 0.f};
  for (int kk = 0; kk < 224; kk += 32) {
    s16x8 pa = *(const s16x8*)(&p_lds[(w * 16 + (l & 15)) * 232 + kk + (l >> 4) * 8]);
#pragma unroll
    for (int f = 0; f < 4; f++) {
      s16x8 vb = *(const s16x8*)(&v_lds[(f * 16 + (l & 15)) * 232 + kk + (l >> 4) * 8]);
      o[f] = __builtin_amdgcn_mfma_f32_16x16x32_bf16(pa, vb, o[f], 0, 0, 0);
    }
  }
  // --- o -> o_lds (overlaps dead q/k region; q/k reads all completed before prior barrier) ---
#pragma unroll
  for (int f = 0; f < 4; f++)
#pragma unroll
    for (int r = 0; r < 4; r++) {
      int m = mbase + r;
      if (m < N2) o_lds[m * 68 + f * 16 + ncol] = o[f][r];
    }
  __syncthreads();

  // --- cooperative epilogue: coalesced vlT add + gelu + gT store ---
  for (int idx = tid; idx < N2 * 16; idx += 256) {
    int row = idx >> 4, c4 = (idx & 15) << 2;
    f32x4 ov = *(const f32x4*)(&o_lds[row * 68 + c4]);
    size_t go = ((size_t)b * N2 + row) * DH + h * DHEAD + c4;
    s16x4 vv = *(const s16x4*)(vlT + go);
    s16x4 outv;
#pragma unroll
    for (int e = 0; e < 4; e++) {
      float xv = ov[e] + bf2f((u16)vv[e]);
      float g = 0.5f * xv * (1.f + erff(xv * 0.70710678118f));
      outv[e] = (short)f2bf(g);
    }
    *(s16x4*)(gT + go) = outv;
  }
}

extern "C" void kernel_launch(void* const* d_in, const int* in_sizes, int n_in,
                              void* d_out, int out_size, void* d_ws, size_t ws_size,
                              hipStream_t stream) {
  const float* x   = (const float*)d_in[0];
  const float* qlw = (const float*)d_in[1];
  const float* qlb = (const float*)d_in[2];
  const float* qpw = (const float*)d_in[3];
  const float* qpb = (const float*)d_in[4];
  const float* qbs = (const float*)d_in[5];
  const float* qbt = (const float*)d_in[6];
  const float* kw  = (const float*)d_in[7];
  const float* kb  = (const float*)d_in[8];
  const float* kbs = (const float*)d_in[9];
  const float* kbt = (const float*)d_in[10];
  const float* vw  = (const float*)d_in[11];
  const float* vb  = (const float*)d_in[12];
  const float* vbs = (const float*)d_in[13];
  const float* vbt = (const float*)d_in[14];
  const float* vlw = (const float*)d_in[15];
  const float* vlb = (const float*)d_in[16];
  const float* vls = (const float*)d_in[17];
  const float* vlt_in = (const float*)d_in[18];
  const float* pw  = (const float*)d_in[19];
  const float* pb  = (const float*)d_in[20];
  const float* pbs = (const float*)d_in[21];
  const float* pbt = (const float*)d_in[22];
  const float* ab  = (const float*)d_in[23];
  const int*   bidx = (const int*)d_in[24];
  int noff = in_sizes[23] / NUM_HEADS;

  char* ws = (char*)d_ws;
  size_t off = 0;
  auto alloc = [&](size_t bytes) { char* p = ws + off; off += (bytes + 255) & ~(size_t)255; return p; };
  u16* xbT = (u16*)alloc((size_t)BATCH * NPOS * DIM * 2);      // 77.1 MB (aliased by gT later)
  u16* kTm = (u16*)alloc((size_t)BATCH * NPOS * NH_KD * 2);    // 25.7 MB
  u16* qlT = (u16*)alloc((size_t)BATCH * N2 * DIM * 2);        // 19.3 MB
  u16* qTm = (u16*)alloc((size_t)BATCH * N2 * NH_KD * 2);      //  6.4 MB
  u16* v4m = (u16*)alloc((size_t)BATCH * DH * NPOS * 2);       // 102.8 MB
  u16* vlTm = (u16*)alloc((size_t)BATCH * N2 * DH * 2);        // 25.7 MB
  float* bxp = (float*)alloc((size_t)NUM_HEADS * N2 * 16 * 16 * 4);  // 0.8 MB
  u16* kwb = (u16*)alloc((size_t)NH_KD * DIM * 2);
  u16* vwb = (u16*)alloc((size_t)DH * DIM * 2);
  u16* qwb = (u16*)alloc((size_t)NH_KD * DIM * 2);
  u16* pwb = (u16*)alloc((size_t)OUT_DIM * DH * 2);
  u16* gTm = xbT;  // alias: all xbT readers complete before k_attn writes gT

  k_f2bf<<<(NH_KD * DIM + 255) / 256, 256, 0, stream>>>(kw, kwb, NH_KD * DIM);
  k_f2bf<<<(DH * DIM + 255) / 256, 256, 0, stream>>>(vw, vwb, DH * DIM);
  k_f2bf<<<(NH_KD * DIM + 255) / 256, 256, 0, stream>>>(qpw, qwb, NH_KD * DIM);
  k_f2bf<<<(OUT_DIM * DH + 255) / 256, 256, 0, stream>>>(pw, pwb, OUT_DIM * DH);
  k_biasx_p<<<(NUM_HEADS * N2 * 16 * 16 + 255) / 256, 256, 0, stream>>>(ab, bidx, bxp, noff);

  k_transpose<<<dim3(6, BATCH), 256, 0, stream>>>(x, xbT);
  k_dwconv_q<<<dim3((N2 * DIM + 255) / 256, BATCH), 256, 0, stream>>>(xbT, qlw, qlb, qlT);

  // k: C[b][n][o]  (m = n_spatial, ch = col)
  k_gemm_bt<8, false, false><<<dim3(4, BATCH), 256, 0, stream>>>(
      xbT, kwb, kTm, kb, kbs, kbt,
      (long)NPOS * DIM, 0, (long)NPOS * NH_KD, DIM, NPOS, NH_KD, NPOS, NH_KD, NH_KD);
  // v: C[b][o][n]  (m = channel)
  k_gemm_bt<13, true, false><<<dim3(8, BATCH), 256, 0, stream>>>(
      vwb, xbT, v4m, vb, vbs, vbt,
      0, (long)NPOS * DIM, (long)DH * NPOS, DIM, DH, NPOS, DH, NPOS, NPOS);
  // q: C[b][n2][o]
  k_gemm_bt<8, false, false><<<dim3(1, BATCH), 256, 0, stream>>>(
      qlT, qwb, qTm, qpb, qbs, qbt,
      (long)N2 * DIM, 0, (long)N2 * NH_KD, DIM, N2, NH_KD, N2, NH_KD, NH_KD);

  k_dwconv_v<<<dim3(8, BATCH), 256, 0, stream>>>(v4m, vlw, vlb, vls, vlt_in, vlTm);
  k_attn_mfma<<<dim3(NUM_HEADS, BATCH), 256, 0, stream>>>(qTm, kTm, v4m, bxp, vlTm, gTm);

  // p: C[b][o][n2] -> d_out f32
  k_gemm_bt<4, true, true><<<dim3(12, BATCH), 256, 0, stream>>>(
      pwb, gTm, d_out, pb, pbs, pbt,
      0, (long)N2 * DH, (long)OUT_DIM * N2, DH, OUT_DIM, N2, OUT_DIM, N2, N2);
}

// Round 7
// 508.554 us; speedup vs baseline: 1.5305x; 1.4273x over previous
//
#include <hip/hip_runtime.h>
#include <math.h>

#define DIM 384
#define NUM_HEADS 8
#define RES 14
#define RES2 7
#define NPOS 196
#define N2 49
#define DHEAD 64
#define NH_KD 128
#define DH 512
#define OUT_DIM 768
#define BATCH 512
#define SCALE_Q 0.25f

typedef unsigned short u16;
typedef short s16x8 __attribute__((ext_vector_type(8)));
typedef short s16x4 __attribute__((ext_vector_type(4)));
typedef float f32x4 __attribute__((ext_vector_type(4)));
typedef unsigned int u32x2 __attribute__((ext_vector_type(2)));

__device__ __forceinline__ float bf2f(u16 u) {
  union { unsigned int i; float f; } v; v.i = ((unsigned int)u) << 16; return v.f;
}
__device__ __forceinline__ u16 f2bf(float f) {
  union { unsigned int i; float f; } v; v.f = f;
  unsigned int r = v.i + 0x7fffu + ((v.i >> 16) & 1u);
  return (u16)(r >> 16);
}

#define GLD16(gp, lp) __builtin_amdgcn_global_load_lds( \
    (const __attribute__((address_space(1))) void*)(gp), \
    (__attribute__((address_space(3))) void*)(lp), 16, 0, 0)

// ---------- small prep kernels ----------
__global__ __launch_bounds__(256) void k_f2bf(const float* __restrict__ s, u16* __restrict__ d, int n) {
  int i = blockIdx.x * 256 + threadIdx.x;
  if (i < n) d[i] = f2bf(s[i]);
}

// bias permuted to MFMA fragment order: bxp[h][m][ncol][16], entry f = bias(h, m, n=f*16+ncol), 0 if n>=196
__global__ __launch_bounds__(256) void k_biasx_p(const float* __restrict__ ab, const int* __restrict__ idxs,
                                                 float* __restrict__ bxp, int noff) {
  int i = blockIdx.x * 256 + threadIdx.x;
  if (i >= NUM_HEADS * N2 * 16 * 16) return;
  int f = i & 15, c = (i >> 4) & 15;
  int m = (i >> 8) % N2, h = i / (N2 * 256);
  int n = f * 16 + c;
  bxp[i] = (n < NPOS) ? ab[h * noff + idxs[m * NPOS + n]] : 0.f;
}

// ---------- x (f32 [b][384][196]) -> xbT (bf16 [b][196][384]) ----------
__global__ __launch_bounds__(256) void k_transpose(const float* __restrict__ x, u16* __restrict__ xt) {
  int b = blockIdx.y, c0 = blockIdx.x * 64;
  __shared__ u16 tile[64][196];
  int tid = threadIdx.x, wave = tid >> 6, lane = tid & 63;
  const float* xb = x + (size_t)b * DIM * NPOS;
  for (int r = wave; r < 64; r += 4) {
    const float* row = xb + (size_t)(c0 + r) * NPOS;
    tile[r][lane]       = f2bf(row[lane]);
    tile[r][lane + 64]  = f2bf(row[lane + 64]);
    tile[r][lane + 128] = f2bf(row[lane + 128]);
    if (lane < 4) tile[r][lane + 192] = f2bf(row[lane + 192]);
  }
  __syncthreads();
  u16* xtb = xt + (size_t)b * NPOS * DIM;
  for (int n = wave; n < NPOS; n += 4)
    xtb[(size_t)n * DIM + c0 + lane] = tile[lane][n];
}

// ---------- ql = dwconv_s2(x) + b + x[::2,::2]  -> qlT (bf16 [b][49][384]) ----------
__global__ __launch_bounds__(256) void k_dwconv_q(const u16* __restrict__ xt, const float* __restrict__ w,
                                                  const float* __restrict__ bias, u16* __restrict__ qlt) {
  int b = blockIdx.y;
  int lid = blockIdx.x * 256 + threadIdx.x;
  if (lid >= N2 * DIM) return;
  int n2 = lid / DIM, c = lid % DIM;
  int r = n2 / RES2, s = n2 % RES2;
  const u16* xb = xt + (size_t)b * NPOS * DIM;
  float acc = bias[c];
#pragma unroll
  for (int dy = 0; dy < 3; dy++) {
    int ry = 2 * r - 1 + dy;
    if (ry < 0 || ry >= RES) continue;
#pragma unroll
    for (int dx = 0; dx < 3; dx++) {
      int sx = 2 * s - 1 + dx;
      if (sx < 0 || sx >= RES) continue;
      acc += w[c * 9 + dy * 3 + dx] * bf2f(xb[(size_t)(ry * RES + sx) * DIM + c]);
    }
  }
  acc += bf2f(xb[(size_t)(2 * r * RES + 2 * s) * DIM + c]);  // strided residual
  qlt[((size_t)b * N2 + n2) * DIM + c] = f2bf(acc);
}

// ---------- flattened GEMM: C = A[M][K] x B[N][K]^T, both K-contiguous bf16 ----------
// 128x128x32 tile, 4 waves (2x2 quadrants), global_load_lds(16B) staging into LINEAR LDS.
// Per K-step each matrix tile = 128 rows x 64B = 8 chunks of 1KB; wave w stages chunks
// w*2, w*2+1 (one GLD16 = 64 lanes x 16B = 1 chunk).  [r6 bug: w*4+c staged 16 chunks ->
// LDS overflow + OOB global reads; fixed]
// Source pre-swizzle (m173/rule21): lane fetches global granule (l&3)^((l>>3)&3), so
// logical granule g of row r sits at physical g^((r>>1)&3); frag reads un-swizzle with
// rg8 = ((l>>4)^((l>>1)&3))*8 -> quarter-wave-conflict-free reads, dense linear writes.
// SPLN=0: out[m*ldc + n] (ch=n).  SPLN>0: out[(n/SPLN)*bstride + m*SPLN + n%SPLN] (ch=m).
template <int SPLN, bool F32OUT>
__global__ __launch_bounds__(256) void k_gemm_flat(
    const u16* __restrict__ A, const u16* __restrict__ B, void* __restrict__ C,
    const float* __restrict__ cb, const float* __restrict__ bns, const float* __restrict__ bnt,
    int K, int NMT, int ldc, long bstride) {
  __shared__ __align__(16) u16 a_lds[128 * 32];
  __shared__ __align__(16) u16 b_lds[128 * 32];
  int nwg = gridDim.x, bx = blockIdx.x;
  int wg = ((nwg & 7) == 0) ? ((bx & 7) * (nwg >> 3) + (bx >> 3)) : bx;  // XCD-bijective
  int mt = wg % NMT, nt = wg / NMT;                                      // m fastest: j-tile shared on-XCD
  int m0 = mt * 128, n0 = nt * 128;
  int tid = threadIdx.x, w = tid >> 6, l = tid & 63;

  // staging geometry: chunk = 1KB = 16 rows x 64B; wave w owns chunks w*2, w*2+1
  int srow = l >> 2;
  int scol = ((l & 3) ^ ((l >> 3) & 3)) * 8;   // pre-swizzled source granule
  const u16* asrc[2]; const u16* bsrc[2];
#pragma unroll
  for (int c = 0; c < 2; c++) {
    int chunk = w * 2 + c;
    asrc[c] = A + (size_t)(m0 + chunk * 16 + srow) * K + scol;
    bsrc[c] = B + (size_t)(n0 + chunk * 16 + srow) * K + scol;
  }
  char* adst = (char*)a_lds + (w * 2) * 1024 + l * 16;
  char* bdst = (char*)b_lds + (w * 2) * 1024 + l * 16;

  f32x4 acc[4][4];
#pragma unroll
  for (int i = 0; i < 4; i++)
#pragma unroll
    for (int j = 0; j < 4; j++) acc[i][j] = (f32x4){0.f, 0.f, 0.f, 0.f};

  int wm = w >> 1, wn = w & 1;
  int rg8 = ((l >> 4) ^ ((l >> 1) & 3)) * 8;   // un-swizzling read granule
  int arow = wm * 64 + (l & 15);
  int brow = wn * 64 + (l & 15);

  for (int kk = 0; kk < K; kk += 32) {
#pragma unroll
    for (int c = 0; c < 2; c++) {
      GLD16(asrc[c] + kk, adst + c * 1024);
      GLD16(bsrc[c] + kk, bdst + c * 1024);
    }
    __syncthreads();                 // compiler drains vmcnt before barrier
    s16x8 af[4], bf[4];
#pragma unroll
    for (int i = 0; i < 4; i++) {
      af[i] = *(const s16x8*)(&a_lds[(arow + i * 16) * 32 + rg8]);
      bf[i] = *(const s16x8*)(&b_lds[(brow + i * 16) * 32 + rg8]);
    }
#pragma unroll
    for (int i = 0; i < 4; i++)
#pragma unroll
      for (int j = 0; j < 4; j++)
        acc[i][j] = __builtin_amdgcn_mfma_f32_16x16x32_bf16(af[i], bf[j], acc[i][j], 0, 0, 0);
    __syncthreads();
  }

  int ncol = l & 15, mq = (l >> 4) * 4;
#pragma unroll
  for (int i = 0; i < 4; i++) {
#pragma unroll
    for (int j = 0; j < 4; j++) {
      int n = n0 + wn * 64 + j * 16 + ncol;
#pragma unroll
      for (int r = 0; r < 4; r++) {
        int m = m0 + wm * 64 + i * 16 + mq + r;
        int ch = SPLN ? m : n;
        float val = acc[i][j][r] * bns[ch] + (cb[ch] * bns[ch] + bnt[ch]);
        size_t o;
        if (SPLN) o = (size_t)(n / SPLN) * bstride + (size_t)m * SPLN + (n % SPLN);
        else      o = (size_t)m * ldc + n;
        if (F32OUT) ((float*)C)[o] = val;
        else        ((u16*)C)[o] = f2bf(val);
      }
    }
  }
}

// ---------- v_local = BN(dwconv_s2(v4) + b) -> vlT (bf16 [b][49][512]) ----------
__global__ __launch_bounds__(256) void k_dwconv_v(const u16* __restrict__ v4, const float* __restrict__ w,
    const float* __restrict__ bias, const float* __restrict__ bns, const float* __restrict__ bnt,
    u16* __restrict__ vlt) {
  int b = blockIdx.y, ct = blockIdx.x;
  __shared__ u16 tile[64][196];
  int tid = threadIdx.x, wave = tid >> 6, lane = tid & 63;
  const u16* vbp = v4 + ((size_t)b * DH + ct * 64) * NPOS;
  for (int r = wave; r < 64; r += 4) {
    const u16* row = vbp + (size_t)r * NPOS;
    tile[r][lane]       = row[lane];
    tile[r][lane + 64]  = row[lane + 64];
    tile[r][lane + 128] = row[lane + 128];
    if (lane < 4) tile[r][lane + 192] = row[lane + 192];
  }
  __syncthreads();
  for (int idx = tid; idx < 64 * N2; idx += 256) {
    int cl = idx & 63, n2 = idx >> 6;
    int ch = ct * 64 + cl;
    int r = n2 / RES2, s = n2 % RES2;
    float acc = bias[ch];
#pragma unroll
    for (int dy = 0; dy < 3; dy++) {
      int ry = 2 * r - 1 + dy;
      if (ry < 0 || ry >= RES) continue;
#pragma unroll
      for (int dx = 0; dx < 3; dx++) {
        int sx = 2 * s - 1 + dx;
        if (sx < 0 || sx >= RES) continue;
        acc += w[ch * 9 + dy * 3 + dx] * bf2f(tile[cl][ry * RES + sx]);
      }
    }
    vlt[((size_t)b * N2 + n2) * DH + ch] = f2bf(acc * bns[ch] + bnt[ch]);
  }
}

// ---------- MFMA attention per (b,h) ----------
// P/V LDS rows stride 232 u16 = 116 dw; 116 mod 32 = 20 -> 8 distinct bank classes -> 2-way (free).
// o_lds (f32, stride 68) overlaps the dead q/k region: 49*68*4 = 13.3 KB < 17.4 KB.
__global__ __launch_bounds__(256) void k_attn_mfma(const u16* __restrict__ qT, const u16* __restrict__ kT,
    const u16* __restrict__ v4, const float* __restrict__ bxp, const u16* __restrict__ vlT,
    u16* __restrict__ gT) {
  int h = blockIdx.x, b = blockIdx.y;
  __shared__ __align__(16) u16 smem[64 * 32 + 208 * 32 + 64 * 232 + 64 * 232];
  u16* q_lds = smem;                       // 64*32
  u16* k_lds = smem + 64 * 32;             // 208*32
  u16* p_lds = smem + 64 * 32 + 208 * 32;  // 64*232
  u16* v_lds = p_lds + 64 * 232;           // 64*232
  float* o_lds = (float*)smem;             // overlaps q_lds+k_lds
  int tid = threadIdx.x, w = tid >> 6, l = tid & 63;

  // --- stage q: row = tid>>2, part = tid&3 (parts 2,3 = K-pad zeros) ---
  {
    int row = tid >> 2, part = tid & 3;
    s16x8 val = (s16x8){0, 0, 0, 0, 0, 0, 0, 0};
    if (part < 2 && row < N2)
      val = *(const s16x8*)(qT + ((size_t)b * N2 + row) * NH_KD + h * 16 + part * 8);
    *(s16x8*)(&q_lds[row * 32 + part * 8]) = val;
  }
  // --- stage k ---
  for (int row = tid >> 2; row < 208; row += 64) {
    int part = tid & 3;
    s16x8 val = (s16x8){0, 0, 0, 0, 0, 0, 0, 0};
    if (part < 2 && row < NPOS)
      val = *(const s16x8*)(kT + ((size_t)b * NPOS + row) * NH_KD + h * 16 + part * 8);
    *(s16x8*)(&k_lds[row * 32 + part * 8]) = val;
  }
  // --- stage v: wave w rows w*16..w*16+15; one 8B load per lane per row (49*8B = full 392B row) ---
  for (int r = 0; r < 16; r++) {
    int row = w * 16 + r;
    const u32x2* gsrc = (const u32x2*)(v4 + ((size_t)b * DH + h * DHEAD + row) * NPOS);
    u32x2* dst = (u32x2*)&v_lds[row * 232];
    if (l < 49)       dst[l] = gsrc[l];
    else if (l < 56)  dst[49 + (l - 49)] = (u32x2){0, 0};   // dw 98..111 zero
  }
  // --- zero p_lds cols 208..223 (dwords 104..111) ---
  for (int idx = tid; idx < 64 * 8; idx += 256)
    ((uint*)&p_lds[(idx >> 3) * 232])[104 + (idx & 7)] = 0;

  // --- bias fragment loads (issued before barrier; independent of LDS) ---
  int mbase = w * 16 + (l >> 4) * 4;
  int ncol = l & 15;
  f32x4 bq[4][4];
#pragma unroll
  for (int r = 0; r < 4; r++) {
    int mm = mbase + r; if (mm > N2 - 1) mm = N2 - 1;
    const float* bb = bxp + (((size_t)h * N2 + mm) * 16 + ncol) * 16;
#pragma unroll
    for (int q = 0; q < 4; q++) bq[r][q] = *(const f32x4*)(bb + q * 4);
  }
  __syncthreads();

  // --- QK^T: wave w owns rows w*16..w*16+15; 13 col-frags ---
  f32x4 s[13];
  {
    s16x8 af = *(const s16x8*)(&q_lds[(w * 16 + (l & 15)) * 32 + (l >> 4) * 8]);
#pragma unroll
    for (int f = 0; f < 13; f++) {
      s16x8 bf = *(const s16x8*)(&k_lds[(f * 16 + (l & 15)) * 32 + (l >> 4) * 8]);
      s[f] = __builtin_amdgcn_mfma_f32_16x16x32_bf16(af, bf, (f32x4){0.f, 0.f, 0.f, 0.f}, 0, 0, 0);
    }
  }
  // --- scale + bias + mask (C layout: col = l&15, row = (l>>4)*4 + reg) ---
#pragma unroll
  for (int f = 0; f < 13; f++) {
    int n = f * 16 + ncol;
#pragma unroll
    for (int r = 0; r < 4; r++) {
      int m = mbase + r;
      s[f][r] = (m < N2 && n < NPOS) ? s[f][r] * SCALE_Q + bq[r][f >> 2][f & 3] : -1e30f;
    }
  }
  // --- softmax: rows live in 16-lane groups -> shfl_xor 1,2,4,8 ---
#pragma unroll
  for (int r = 0; r < 4; r++) {
    float mx = s[0][r];
#pragma unroll
    for (int f = 1; f < 13; f++) mx = fmaxf(mx, s[f][r]);
    mx = fmaxf(mx, __shfl_xor(mx, 1)); mx = fmaxf(mx, __shfl_xor(mx, 2));
    mx = fmaxf(mx, __shfl_xor(mx, 4)); mx = fmaxf(mx, __shfl_xor(mx, 8));
    float sum = 0.f;
#pragma unroll
    for (int f = 0; f < 13; f++) { s[f][r] = __expf(s[f][r] - mx); sum += s[f][r]; }
    sum += __shfl_xor(sum, 1); sum += __shfl_xor(sum, 2);
    sum += __shfl_xor(sum, 4); sum += __shfl_xor(sum, 8);
    float inv = 1.f / sum;
#pragma unroll
    for (int f = 0; f < 13; f++) s[f][r] *= inv;
  }
  // --- P -> LDS (bf16), wave-local rows ---
#pragma unroll
  for (int f = 0; f < 13; f++) {
    int n = f * 16 + ncol;
#pragma unroll
    for (int r = 0; r < 4; r++)
      p_lds[(mbase + r) * 232 + n] = f2bf(s[f][r]);
  }
  __syncthreads();

  // --- PV: A = P rows (wave-local m-tile), B = V rows (d), K = 224 ---
  f32x4 o[4];
#pragma unroll
  for (int f = 0; f < 4; f++) o[f] = (f32x4){0.f, 0.f, 0.f, 0.f};
  for (int kk = 0; kk < 224; kk += 32) {
    s16x8 pa = *(const s16x8*)(&p_lds[(w * 16 + (l & 15)) * 232 + kk + (l >> 4) * 8]);
#pragma unroll
    for (int f = 0; f < 4; f++) {
      s16x8 vb = *(const s16x8*)(&v_lds[(f * 16 + (l & 15)) * 232 + kk + (l >> 4) * 8]);
      o[f] = __builtin_amdgcn_mfma_f32_16x16x32_bf16(pa, vb, o[f], 0, 0, 0);
    }
  }
  // --- o -> o_lds (overlaps dead q/k region; q/k reads all completed before prior barrier) ---
#pragma unroll
  for (int f = 0; f < 4; f++)
#pragma unroll
    for (int r = 0; r < 4; r++) {
      int m = mbase + r;
      if (m < N2) o_lds[m * 68 + f * 16 + ncol] = o[f][r];
    }
  __syncthreads();

  // --- cooperative epilogue: coalesced vlT add + gelu + gT store ---
  for (int idx = tid; idx < N2 * 16; idx += 256) {
    int row = idx >> 4, c4 = (idx & 15) << 2;
    f32x4 ov = *(const f32x4*)(&o_lds[row * 68 + c4]);
    size_t go = ((size_t)b * N2 + row) * DH + h * DHEAD + c4;
    s16x4 vv = *(const s16x4*)(vlT + go);
    s16x4 outv;
#pragma unroll
    for (int e = 0; e < 4; e++) {
      float xv = ov[e] + bf2f((u16)vv[e]);
      float g = 0.5f * xv * (1.f + erff(xv * 0.70710678118f));
      outv[e] = (short)f2bf(g);
    }
    *(s16x4*)(gT + go) = outv;
  }
}

extern "C" void kernel_launch(void* const* d_in, const int* in_sizes, int n_in,
                              void* d_out, int out_size, void* d_ws, size_t ws_size,
                              hipStream_t stream) {
  const float* x   = (const float*)d_in[0];
  const float* qlw = (const float*)d_in[1];
  const float* qlb = (const float*)d_in[2];
  const float* qpw = (const float*)d_in[3];
  const float* qpb = (const float*)d_in[4];
  const float* qbs = (const float*)d_in[5];
  const float* qbt = (const float*)d_in[6];
  const float* kw  = (const float*)d_in[7];
  const float* kb  = (const float*)d_in[8];
  const float* kbs = (const float*)d_in[9];
  const float* kbt = (const float*)d_in[10];
  const float* vw  = (const float*)d_in[11];
  const float* vb  = (const float*)d_in[12];
  const float* vbs = (const float*)d_in[13];
  const float* vbt = (const float*)d_in[14];
  const float* vlw = (const float*)d_in[15];
  const float* vlb = (const float*)d_in[16];
  const float* vls = (const float*)d_in[17];
  const float* vlt_in = (const float*)d_in[18];
  const float* pw  = (const float*)d_in[19];
  const float* pb  = (const float*)d_in[20];
  const float* pbs = (const float*)d_in[21];
  const float* pbt = (const float*)d_in[22];
  const float* ab  = (const float*)d_in[23];
  const int*   bidx = (const int*)d_in[24];
  int noff = in_sizes[23] / NUM_HEADS;

  char* ws = (char*)d_ws;
  size_t off = 0;
  auto alloc = [&](size_t bytes) { char* p = ws + off; off += (bytes + 255) & ~(size_t)255; return p; };
  u16* xbT = (u16*)alloc((size_t)BATCH * NPOS * DIM * 2);      // 77.1 MB (aliased by gT later)
  u16* kTm = (u16*)alloc((size_t)BATCH * NPOS * NH_KD * 2);    // 25.7 MB
  u16* qlT = (u16*)alloc((size_t)BATCH * N2 * DIM * 2);        // 19.3 MB
  u16* qTm = (u16*)alloc((size_t)BATCH * N2 * NH_KD * 2);      //  6.4 MB
  u16* v4m = (u16*)alloc((size_t)BATCH * DH * NPOS * 2);       // 102.8 MB
  u16* vlTm = (u16*)alloc((size_t)BATCH * N2 * DH * 2);        // 25.7 MB
  float* bxp = (float*)alloc((size_t)NUM_HEADS * N2 * 16 * 16 * 4);  // 0.8 MB
  u16* kwb = (u16*)alloc((size_t)NH_KD * DIM * 2);
  u16* vwb = (u16*)alloc((size_t)DH * DIM * 2);
  u16* qwb = (u16*)alloc((size_t)NH_KD * DIM * 2);
  u16* pwb = (u16*)alloc((size_t)OUT_DIM * DH * 2);
  u16* gTm = xbT;  // alias: all xbT readers complete before k_attn writes gT

  k_f2bf<<<(NH_KD * DIM + 255) / 256, 256, 0, stream>>>(kw, kwb, NH_KD * DIM);
  k_f2bf<<<(DH * DIM + 255) / 256, 256, 0, stream>>>(vw, vwb, DH * DIM);
  k_f2bf<<<(NH_KD * DIM + 255) / 256, 256, 0, stream>>>(qpw, qwb, NH_KD * DIM);
  k_f2bf<<<(OUT_DIM * DH + 255) / 256, 256, 0, stream>>>(pw, pwb, OUT_DIM * DH);
  k_biasx_p<<<(NUM_HEADS * N2 * 16 * 16 + 255) / 256, 256, 0, stream>>>(ab, bidx, bxp, noff);

  k_transpose<<<dim3(6, BATCH), 256, 0, stream>>>(x, xbT);
  k_dwconv_q<<<dim3((N2 * DIM + 255) / 256, BATCH), 256, 0, stream>>>(xbT, qlw, qlb, qlT);

  // k: A=xbT[100352][384] (m=j), B=kwb[128][384] (n=ch) -> kTm[j][128]; 784 m-tiles x 1 n-tile
  k_gemm_flat<0, false><<<784, 256, 0, stream>>>(
      xbT, kwb, kTm, kb, kbs, kbt, DIM, 784, NH_KD, 0);
  // v: A=vwb[512][384] (m=ch), B=xbT (n=j) -> v4m[b][512][196]; 4 m-tiles x 784 n-tiles
  k_gemm_flat<NPOS, false><<<3136, 256, 0, stream>>>(
      vwb, xbT, v4m, vb, vbs, vbt, DIM, 4, 0, (long)DH * NPOS);
  // q: A=qlT[25088][384] (m=j), B=qwb (n=ch) -> qTm[j][128]; 196 m-tiles x 1 n-tile
  k_gemm_flat<0, false><<<196, 256, 0, stream>>>(
      qlT, qwb, qTm, qpb, qbs, qbt, DIM, 196, NH_KD, 0);

  k_dwconv_v<<<dim3(8, BATCH), 256, 0, stream>>>(v4m, vlw, vlb, vls, vlt_in, vlTm);
  k_attn_mfma<<<dim3(NUM_HEADS, BATCH), 256, 0, stream>>>(qTm, kTm, v4m, bxp, vlTm, gTm);

  // p: A=pwb[768][512] (m=ch), B=gTm[25088][512] (n=j) -> d_out[b][768][49] f32; 6 x 196
  k_gemm_flat<N2, true><<<1176, 256, 0, stream>>>(
      pwb, gTm, d_out, pb, pbs, pbt, DH, 6, 0, (long)OUT_DIM * N2);
}

// Round 8
// 465.846 us; speedup vs baseline: 1.6708x; 1.0917x over previous
//
#include <hip/hip_runtime.h>
#include <math.h>

#define DIM 384
#define NUM_HEADS 8
#define RES 14
#define RES2 7
#define NPOS 196
#define N2 49
#define DHEAD 64
#define NH_KD 128
#define DH 512
#define OUT_DIM 768
#define BATCH 512
#define SCALE_Q 0.25f

typedef unsigned short u16;
typedef short s16x8 __attribute__((ext_vector_type(8)));
typedef short s16x4 __attribute__((ext_vector_type(4)));
typedef float f32x4 __attribute__((ext_vector_type(4)));
typedef unsigned int u32x2 __attribute__((ext_vector_type(2)));

__device__ __forceinline__ float bf2f(u16 u) {
  union { unsigned int i; float f; } v; v.i = ((unsigned int)u) << 16; return v.f;
}
__device__ __forceinline__ u16 f2bf(float f) {
  union { unsigned int i; float f; } v; v.f = f;
  unsigned int r = v.i + 0x7fffu + ((v.i >> 16) & 1u);
  return (u16)(r >> 16);
}

#define GLD16(gp, lp) __builtin_amdgcn_global_load_lds( \
    (const __attribute__((address_space(1))) void*)(gp), \
    (__attribute__((address_space(3))) void*)(lp), 16, 0, 0)

// ---------- small prep kernels ----------
__global__ __launch_bounds__(256) void k_f2bf(const float* __restrict__ s, u16* __restrict__ d, int n) {
  int i = blockIdx.x * 256 + threadIdx.x;
  if (i < n) d[i] = f2bf(s[i]);
}

// bias permuted to MFMA fragment order: bxp[h][m][ncol][16], entry f = bias(h, m, n=f*16+ncol), 0 if n>=196
__global__ __launch_bounds__(256) void k_biasx_p(const float* __restrict__ ab, const int* __restrict__ idxs,
                                                 float* __restrict__ bxp, int noff) {
  int i = blockIdx.x * 256 + threadIdx.x;
  if (i >= NUM_HEADS * N2 * 16 * 16) return;
  int f = i & 15, c = (i >> 4) & 15;
  int m = (i >> 8) % N2, h = i / (N2 * 256);
  int n = f * 16 + c;
  bxp[i] = (n < NPOS) ? ab[h * noff + idxs[m * NPOS + n]] : 0.f;
}

// ---------- x (f32 [b][384][196]) -> xbT (bf16 [b][196][384]) ----------
__global__ __launch_bounds__(256) void k_transpose(const float* __restrict__ x, u16* __restrict__ xt) {
  int b = blockIdx.y, c0 = blockIdx.x * 64;
  __shared__ u16 tile[64][196];
  int tid = threadIdx.x, wave = tid >> 6, lane = tid & 63;
  const float* xb = x + (size_t)b * DIM * NPOS;
  for (int r = wave; r < 64; r += 4) {
    const float* row = xb + (size_t)(c0 + r) * NPOS;
    tile[r][lane]       = f2bf(row[lane]);
    tile[r][lane + 64]  = f2bf(row[lane + 64]);
    tile[r][lane + 128] = f2bf(row[lane + 128]);
    if (lane < 4) tile[r][lane + 192] = f2bf(row[lane + 192]);
  }
  __syncthreads();
  u16* xtb = xt + (size_t)b * NPOS * DIM;
  for (int n = wave; n < NPOS; n += 4)
    xtb[(size_t)n * DIM + c0 + lane] = tile[lane][n];
}

// ---------- ql = dwconv_s2(x) + b + x[::2,::2]  -> qlT (bf16 [b][49][384]) ----------
__global__ __launch_bounds__(256) void k_dwconv_q(const u16* __restrict__ xt, const float* __restrict__ w,
                                                  const float* __restrict__ bias, u16* __restrict__ qlt) {
  int b = blockIdx.y;
  int lid = blockIdx.x * 256 + threadIdx.x;
  if (lid >= N2 * DIM) return;
  int n2 = lid / DIM, c = lid % DIM;
  int r = n2 / RES2, s = n2 % RES2;
  const u16* xb = xt + (size_t)b * NPOS * DIM;
  float acc = bias[c];
#pragma unroll
  for (int dy = 0; dy < 3; dy++) {
    int ry = 2 * r - 1 + dy;
    if (ry < 0 || ry >= RES) continue;
#pragma unroll
    for (int dx = 0; dx < 3; dx++) {
      int sx = 2 * s - 1 + dx;
      if (sx < 0 || sx >= RES) continue;
      acc += w[c * 9 + dy * 3 + dx] * bf2f(xb[(size_t)(ry * RES + sx) * DIM + c]);
    }
  }
  acc += bf2f(xb[(size_t)(2 * r * RES + 2 * s) * DIM + c]);  // strided residual
  qlt[((size_t)b * N2 + n2) * DIM + c] = f2bf(acc);
}

// ---------- flattened GEMM: C = A[M][K] x B[N][K]^T, both K-contiguous bf16 ----------
// 128x128x32 tile, 4 waves (2x2 quadrants), global_load_lds(16B) staging into LINEAR LDS.
// Per K-step each matrix tile = 128 rows x 64B = 8 chunks of 1KB; wave w stages chunks
// w*2, w*2+1 (one GLD16 = 64 lanes x 16B = 1 chunk).
// Source pre-swizzle (m173/rule21): lane fetches global granule (l&3)^((l>>3)&3), so
// logical granule g of row r sits at physical g^((r>>1)&3); frag reads un-swizzle with
// rg8 = ((l>>4)^((l>>1)&3))*8 -> quarter-wave-conflict-free reads, dense linear writes.
// SPLN=0: out[m*ldc + n] (ch=n).  SPLN>0: out[(n/SPLN)*bstride + m*SPLN + n%SPLN] (ch=m).
template <int SPLN, bool F32OUT>
__global__ __launch_bounds__(256) void k_gemm_flat(
    const u16* __restrict__ A, const u16* __restrict__ B, void* __restrict__ C,
    const float* __restrict__ cb, const float* __restrict__ bns, const float* __restrict__ bnt,
    int K, int NMT, int ldc, long bstride) {
  __shared__ __align__(16) u16 a_lds[128 * 32];
  __shared__ __align__(16) u16 b_lds[128 * 32];
  int nwg = gridDim.x, bx = blockIdx.x;
  int wg = ((nwg & 7) == 0) ? ((bx & 7) * (nwg >> 3) + (bx >> 3)) : bx;  // XCD-bijective
  int mt = wg % NMT, nt = wg / NMT;                                      // m fastest: j-tile shared on-XCD
  int m0 = mt * 128, n0 = nt * 128;
  int tid = threadIdx.x, w = tid >> 6, l = tid & 63;

  // staging geometry: chunk = 1KB = 16 rows x 64B; wave w owns chunks w*2, w*2+1
  int srow = l >> 2;
  int scol = ((l & 3) ^ ((l >> 3) & 3)) * 8;   // pre-swizzled source granule
  const u16* asrc[2]; const u16* bsrc[2];
#pragma unroll
  for (int c = 0; c < 2; c++) {
    int chunk = w * 2 + c;
    asrc[c] = A + (size_t)(m0 + chunk * 16 + srow) * K + scol;
    bsrc[c] = B + (size_t)(n0 + chunk * 16 + srow) * K + scol;
  }
  char* adst = (char*)a_lds + (w * 2) * 1024 + l * 16;
  char* bdst = (char*)b_lds + (w * 2) * 1024 + l * 16;

  f32x4 acc[4][4];
#pragma unroll
  for (int i = 0; i < 4; i++)
#pragma unroll
    for (int j = 0; j < 4; j++) acc[i][j] = (f32x4){0.f, 0.f, 0.f, 0.f};

  int wm = w >> 1, wn = w & 1;
  int rg8 = ((l >> 4) ^ ((l >> 1) & 3)) * 8;   // un-swizzling read granule
  int arow = wm * 64 + (l & 15);
  int brow = wn * 64 + (l & 15);

  for (int kk = 0; kk < K; kk += 32) {
#pragma unroll
    for (int c = 0; c < 2; c++) {
      GLD16(asrc[c] + kk, adst + c * 1024);
      GLD16(bsrc[c] + kk, bdst + c * 1024);
    }
    __syncthreads();                 // compiler drains vmcnt before barrier
    s16x8 af[4], bf[4];
#pragma unroll
    for (int i = 0; i < 4; i++) {
      af[i] = *(const s16x8*)(&a_lds[(arow + i * 16) * 32 + rg8]);
      bf[i] = *(const s16x8*)(&b_lds[(brow + i * 16) * 32 + rg8]);
    }
#pragma unroll
    for (int i = 0; i < 4; i++)
#pragma unroll
      for (int j = 0; j < 4; j++)
        acc[i][j] = __builtin_amdgcn_mfma_f32_16x16x32_bf16(af[i], bf[j], acc[i][j], 0, 0, 0);
    __syncthreads();
  }

  int ncol = l & 15, mq = (l >> 4) * 4;
#pragma unroll
  for (int i = 0; i < 4; i++) {
#pragma unroll
    for (int j = 0; j < 4; j++) {
      int n = n0 + wn * 64 + j * 16 + ncol;
#pragma unroll
      for (int r = 0; r < 4; r++) {
        int m = m0 + wm * 64 + i * 16 + mq + r;
        int ch = SPLN ? m : n;
        float val = acc[i][j][r] * bns[ch] + (cb[ch] * bns[ch] + bnt[ch]);
        size_t o;
        if (SPLN) o = (size_t)(n / SPLN) * bstride + (size_t)m * SPLN + (n % SPLN);
        else      o = (size_t)m * ldc + n;
        if (F32OUT) ((float*)C)[o] = val;
        else        ((u16*)C)[o] = f2bf(val);
      }
    }
  }
}

// ---------- v_local = BN(dwconv_s2(v4) + b) -> vlT (bf16 [b][49][512]) ----------
__global__ __launch_bounds__(256) void k_dwconv_v(const u16* __restrict__ v4, const float* __restrict__ w,
    const float* __restrict__ bias, const float* __restrict__ bns, const float* __restrict__ bnt,
    u16* __restrict__ vlt) {
  int b = blockIdx.y, ct = blockIdx.x;
  __shared__ u16 tile[64][196];
  int tid = threadIdx.x, wave = tid >> 6, lane = tid & 63;
  const u16* vbp = v4 + ((size_t)b * DH + ct * 64) * NPOS;
  for (int r = wave; r < 64; r += 4) {
    const u16* row = vbp + (size_t)r * NPOS;
    tile[r][lane]       = row[lane];
    tile[r][lane + 64]  = row[lane + 64];
    tile[r][lane + 128] = row[lane + 128];
    if (lane < 4) tile[r][lane + 192] = row[lane + 192];
  }
  __syncthreads();
  for (int idx = tid; idx < 64 * N2; idx += 256) {
    int cl = idx & 63, n2 = idx >> 6;
    int ch = ct * 64 + cl;
    int r = n2 / RES2, s = n2 % RES2;
    float acc = bias[ch];
#pragma unroll
    for (int dy = 0; dy < 3; dy++) {
      int ry = 2 * r - 1 + dy;
      if (ry < 0 || ry >= RES) continue;
#pragma unroll
      for (int dx = 0; dx < 3; dx++) {
        int sx = 2 * s - 1 + dx;
        if (sx < 0 || sx >= RES) continue;
        acc += w[ch * 9 + dy * 3 + dx] * bf2f(tile[cl][ry * RES + sx]);
      }
    }
    vlt[((size_t)b * N2 + n2) * DH + ch] = f2bf(acc * bns[ch] + bnt[ch]);
  }
}

// ---------- MFMA attention per (b,h) ----------
// LDS cut 76.8->47.1 KB (3 blocks/CU): v_lds removed — PV B-fragments read directly
// from v4 ([b][512][196] row-major = B-operand layout) as 2x8B loads (row stride 392B
// is 8B-aligned only). Cols >=196 read finite in-ws garbage x P=0.0 -> no contribution.
// Iter-0 V frags issued right after QK^T (hide under softmax); 1-deep pipeline in PV.
// o_lds (f32, stride 68, 13.3 KB) overlaps dead q/k region (17.4 KB).
__global__ __launch_bounds__(256) void k_attn_mfma(const u16* __restrict__ qT, const u16* __restrict__ kT,
    const u16* __restrict__ v4, const float* __restrict__ bxp, const u16* __restrict__ vlT,
    u16* __restrict__ gT) {
  int h = blockIdx.x, b = blockIdx.y;
  __shared__ __align__(16) u16 smem[64 * 32 + 208 * 32 + 64 * 232];
  u16* q_lds = smem;                       // 64*32
  u16* k_lds = smem + 64 * 32;             // 208*32
  u16* p_lds = smem + 64 * 32 + 208 * 32;  // 64*232
  float* o_lds = (float*)smem;             // overlaps q_lds+k_lds
  int tid = threadIdx.x, w = tid >> 6, l = tid & 63;

  // --- stage q: row = tid>>2, part = tid&3 (parts 2,3 = K-pad zeros) ---
  {
    int row = tid >> 2, part = tid & 3;
    s16x8 val = (s16x8){0, 0, 0, 0, 0, 0, 0, 0};
    if (part < 2 && row < N2)
      val = *(const s16x8*)(qT + ((size_t)b * N2 + row) * NH_KD + h * 16 + part * 8);
    *(s16x8*)(&q_lds[row * 32 + part * 8]) = val;
  }
  // --- stage k ---
  for (int row = tid >> 2; row < 208; row += 64) {
    int part = tid & 3;
    s16x8 val = (s16x8){0, 0, 0, 0, 0, 0, 0, 0};
    if (part < 2 && row < NPOS)
      val = *(const s16x8*)(kT + ((size_t)b * NPOS + row) * NH_KD + h * 16 + part * 8);
    *(s16x8*)(&k_lds[row * 32 + part * 8]) = val;
  }
  // --- zero p_lds cols 208..223 (dwords 104..111) ---
  for (int idx = tid; idx < 64 * 8; idx += 256)
    ((uint*)&p_lds[(idx >> 3) * 232])[104 + (idx & 7)] = 0;

  // --- bias fragment loads (issued before barrier; independent of LDS) ---
  int mbase = w * 16 + (l >> 4) * 4;
  int ncol = l & 15;
  f32x4 bq[4][4];
#pragma unroll
  for (int r = 0; r < 4; r++) {
    int mm = mbase + r; if (mm > N2 - 1) mm = N2 - 1;
    const float* bb = bxp + (((size_t)h * N2 + mm) * 16 + ncol) * 16;
#pragma unroll
    for (int q = 0; q < 4; q++) bq[r][q] = *(const f32x4*)(bb + q * 4);
  }
  __syncthreads();

  // --- QK^T: wave w owns rows w*16..w*16+15; 13 col-frags ---
  f32x4 s[13];
  {
    s16x8 af = *(const s16x8*)(&q_lds[(w * 16 + (l & 15)) * 32 + (l >> 4) * 8]);
#pragma unroll
    for (int f = 0; f < 13; f++) {
      s16x8 bf = *(const s16x8*)(&k_lds[(f * 16 + (l & 15)) * 32 + (l >> 4) * 8]);
      s[f] = __builtin_amdgcn_mfma_f32_16x16x32_bf16(af, bf, (f32x4){0.f, 0.f, 0.f, 0.f}, 0, 0, 0);
    }
  }

  // --- V fragment geometry + iter-0 prefetch (hides under softmax) ---
  const u16* vbase = v4 + ((size_t)b * DH + h * DHEAD) * NPOS;
  int vd = l & 15, vq8 = (l >> 4) * 8;
  auto VLOAD = [&](int f, int kk) {
    const u16* p = vbase + (size_t)(f * 16 + vd) * NPOS + kk + vq8;
    s16x8 r;
    ((u32x2*)&r)[0] = *(const u32x2*)(p);        // 8B-aligned
    ((u32x2*)&r)[1] = *(const u32x2*)(p + 4);
    return r;
  };
  s16x8 vb0[4];
#pragma unroll
  for (int f = 0; f < 4; f++) vb0[f] = VLOAD(f, 0);

  // --- scale + bias + mask (C layout: col = l&15, row = (l>>4)*4 + reg) ---
#pragma unroll
  for (int f = 0; f < 13; f++) {
    int n = f * 16 + ncol;
#pragma unroll
    for (int r = 0; r < 4; r++) {
      int m = mbase + r;
      s[f][r] = (m < N2 && n < NPOS) ? s[f][r] * SCALE_Q + bq[r][f >> 2][f & 3] : -1e30f;
    }
  }
  // --- softmax: rows live in 16-lane groups -> shfl_xor 1,2,4,8 ---
#pragma unroll
  for (int r = 0; r < 4; r++) {
    float mx = s[0][r];
#pragma unroll
    for (int f = 1; f < 13; f++) mx = fmaxf(mx, s[f][r]);
    mx = fmaxf(mx, __shfl_xor(mx, 1)); mx = fmaxf(mx, __shfl_xor(mx, 2));
    mx = fmaxf(mx, __shfl_xor(mx, 4)); mx = fmaxf(mx, __shfl_xor(mx, 8));
    float sum = 0.f;
#pragma unroll
    for (int f = 0; f < 13; f++) { s[f][r] = __expf(s[f][r] - mx); sum += s[f][r]; }
    sum += __shfl_xor(sum, 1); sum += __shfl_xor(sum, 2);
    sum += __shfl_xor(sum, 4); sum += __shfl_xor(sum, 8);
    float inv = 1.f / sum;
#pragma unroll
    for (int f = 0; f < 13; f++) s[f][r] *= inv;
  }
  // --- P -> LDS (bf16), wave-local rows ---
#pragma unroll
  for (int f = 0; f < 13; f++) {
    int n = f * 16 + ncol;
#pragma unroll
    for (int r = 0; r < 4; r++)
      p_lds[(mbase + r) * 232 + n] = f2bf(s[f][r]);
  }
  __syncthreads();

  // --- PV: A = P rows (wave-local m-tile), B = V from GLOBAL, 1-deep pipeline, K = 224 ---
  f32x4 o[4];
#pragma unroll
  for (int f = 0; f < 4; f++) o[f] = (f32x4){0.f, 0.f, 0.f, 0.f};
#pragma unroll
  for (int t = 0; t < 7; t++) {
    int kk = t * 32;
    s16x8 vn[4];
    if (t < 6) {
#pragma unroll
      for (int f = 0; f < 4; f++) vn[f] = VLOAD(f, kk + 32);
    }
    s16x8 pa = *(const s16x8*)(&p_lds[(w * 16 + (l & 15)) * 232 + kk + (l >> 4) * 8]);
#pragma unroll
    for (int f = 0; f < 4; f++)
      o[f] = __builtin_amdgcn_mfma_f32_16x16x32_bf16(pa, vb0[f], o[f], 0, 0, 0);
    if (t < 6) {
#pragma unroll
      for (int f = 0; f < 4; f++) vb0[f] = vn[f];
    }
  }
  // --- o -> o_lds (overlaps dead q/k region; q/k reads all completed before prior barrier) ---
#pragma unroll
  for (int f = 0; f < 4; f++)
#pragma unroll
    for (int r = 0; r < 4; r++) {
      int m = mbase + r;
      if (m < N2) o_lds[m * 68 + f * 16 + ncol] = o[f][r];
    }
  __syncthreads();

  // --- cooperative epilogue: coalesced vlT add + gelu + gT store ---
  for (int idx = tid; idx < N2 * 16; idx += 256) {
    int row = idx >> 4, c4 = (idx & 15) << 2;
    f32x4 ov = *(const f32x4*)(&o_lds[row * 68 + c4]);
    size_t go = ((size_t)b * N2 + row) * DH + h * DHEAD + c4;
    s16x4 vv = *(const s16x4*)(vlT + go);
    s16x4 outv;
#pragma unroll
    for (int e = 0; e < 4; e++) {
      float xv = ov[e] + bf2f((u16)vv[e]);
      float g = 0.5f * xv * (1.f + erff(xv * 0.70710678118f));
      outv[e] = (short)f2bf(g);
    }
    *(s16x4*)(gT + go) = outv;
  }
}

extern "C" void kernel_launch(void* const* d_in, const int* in_sizes, int n_in,
                              void* d_out, int out_size, void* d_ws, size_t ws_size,
                              hipStream_t stream) {
  const float* x   = (const float*)d_in[0];
  const float* qlw = (const float*)d_in[1];
  const float* qlb = (const float*)d_in[2];
  const float* qpw = (const float*)d_in[3];
  const float* qpb = (const float*)d_in[4];
  const float* qbs = (const float*)d_in[5];
  const float* qbt = (const float*)d_in[6];
  const float* kw  = (const float*)d_in[7];
  const float* kb  = (const float*)d_in[8];
  const float* kbs = (const float*)d_in[9];
  const float* kbt = (const float*)d_in[10];
  const float* vw  = (const float*)d_in[11];
  const float* vb  = (const float*)d_in[12];
  const float* vbs = (const float*)d_in[13];
  const float* vbt = (const float*)d_in[14];
  const float* vlw = (const float*)d_in[15];
  const float* vlb = (const float*)d_in[16];
  const float* vls = (const float*)d_in[17];
  const float* vlt_in = (const float*)d_in[18];
  const float* pw  = (const float*)d_in[19];
  const float* pb  = (const float*)d_in[20];
  const float* pbs = (const float*)d_in[21];
  const float* pbt = (const float*)d_in[22];
  const float* ab  = (const float*)d_in[23];
  const int*   bidx = (const int*)d_in[24];
  int noff = in_sizes[23] / NUM_HEADS;

  char* ws = (char*)d_ws;
  size_t off = 0;
  auto alloc = [&](size_t bytes) { char* p = ws + off; off += (bytes + 255) & ~(size_t)255; return p; };
  u16* xbT = (u16*)alloc((size_t)BATCH * NPOS * DIM * 2);      // 77.1 MB (aliased by gT later)
  u16* kTm = (u16*)alloc((size_t)BATCH * NPOS * NH_KD * 2);    // 25.7 MB
  u16* qlT = (u16*)alloc((size_t)BATCH * N2 * DIM * 2);        // 19.3 MB
  u16* qTm = (u16*)alloc((size_t)BATCH * N2 * NH_KD * 2);      //  6.4 MB
  u16* v4m = (u16*)alloc((size_t)BATCH * DH * NPOS * 2);       // 102.8 MB
  u16* vlTm = (u16*)alloc((size_t)BATCH * N2 * DH * 2);        // 25.7 MB  (also absorbs attn's 56B OOB V reads)
  float* bxp = (float*)alloc((size_t)NUM_HEADS * N2 * 16 * 16 * 4);  // 0.8 MB
  u16* kwb = (u16*)alloc((size_t)NH_KD * DIM * 2);
  u16* vwb = (u16*)alloc((size_t)DH * DIM * 2);
  u16* qwb = (u16*)alloc((size_t)NH_KD * DIM * 2);
  u16* pwb = (u16*)alloc((size_t)OUT_DIM * DH * 2);
  u16* gTm = xbT;  // alias: all xbT readers complete before k_attn writes gT

  k_f2bf<<<(NH_KD * DIM + 255) / 256, 256, 0, stream>>>(kw, kwb, NH_KD * DIM);
  k_f2bf<<<(DH * DIM + 255) / 256, 256, 0, stream>>>(vw, vwb, DH * DIM);
  k_f2bf<<<(NH_KD * DIM + 255) / 256, 256, 0, stream>>>(qpw, qwb, NH_KD * DIM);
  k_f2bf<<<(OUT_DIM * DH + 255) / 256, 256, 0, stream>>>(pw, pwb, OUT_DIM * DH);
  k_biasx_p<<<(NUM_HEADS * N2 * 16 * 16 + 255) / 256, 256, 0, stream>>>(ab, bidx, bxp, noff);

  k_transpose<<<dim3(6, BATCH), 256, 0, stream>>>(x, xbT);
  k_dwconv_q<<<dim3((N2 * DIM + 255) / 256, BATCH), 256, 0, stream>>>(xbT, qlw, qlb, qlT);

  // k: A=xbT[100352][384] (m=j), B=kwb[128][384] (n=ch) -> kTm[j][128]; 784 m-tiles x 1 n-tile
  k_gemm_flat<0, false><<<784, 256, 0, stream>>>(
      xbT, kwb, kTm, kb, kbs, kbt, DIM, 784, NH_KD, 0);
  // v: A=vwb[512][384] (m=ch), B=xbT (n=j) -> v4m[b][512][196]; 4 m-tiles x 784 n-tiles
  k_gemm_flat<NPOS, false><<<3136, 256, 0, stream>>>(
      vwb, xbT, v4m, vb, vbs, vbt, DIM, 4, 0, (long)DH * NPOS);
  // q: A=qlT[25088][384] (m=j), B=qwb (n=ch) -> qTm[j][128]; 196 m-tiles x 1 n-tile
  k_gemm_flat<0, false><<<196, 256, 0, stream>>>(
      qlT, qwb, qTm, qpb, qbs, qbt, DIM, 196, NH_KD, 0);

  k_dwconv_v<<<dim3(8, BATCH), 256, 0, stream>>>(v4m, vlw, vlb, vls, vlt_in, vlTm);
  k_attn_mfma<<<dim3(NUM_HEADS, BATCH), 256, 0, stream>>>(qTm, kTm, v4m, bxp, vlTm, gTm);

  // p: A=pwb[768][512] (m=ch), B=gTm[25088][512] (n=j) -> d_out[b][768][49] f32; 6 x 196
  k_gemm_flat<N2, true><<<1176, 256, 0, stream>>>(
      pwb, gTm, d_out, pb, pbs, pbt, DH, 6, 0, (long)OUT_DIM * N2);
}

// Round 9
// 413.220 us; speedup vs baseline: 1.8836x; 1.1274x over previous
//
#include <hip/hip_runtime.h>
#include <math.h>

#define DIM 384
#define NUM_HEADS 8
#define RES 14
#define RES2 7
#define NPOS 196
#define N2 49
#define DHEAD 64
#define NH_KD 128
#define DH 512
#define OUT_DIM 768
#define BATCH 512
#define SCALE_Q 0.25f

typedef unsigned short u16;
typedef short s16x8 __attribute__((ext_vector_type(8)));
typedef short s16x4 __attribute__((ext_vector_type(4)));
typedef float f32x4 __attribute__((ext_vector_type(4)));
typedef unsigned int u32x2 __attribute__((ext_vector_type(2)));

__device__ __forceinline__ float bf2f(u16 u) {
  union { unsigned int i; float f; } v; v.i = ((unsigned int)u) << 16; return v.f;
}
__device__ __forceinline__ u16 f2bf(float f) {
  union { unsigned int i; float f; } v; v.f = f;
  unsigned int r = v.i + 0x7fffu + ((v.i >> 16) & 1u);
  return (u16)(r >> 16);
}

#define GLD16(gp, lp) __builtin_amdgcn_global_load_lds( \
    (const __attribute__((address_space(1))) void*)(gp), \
    (__attribute__((address_space(3))) void*)(lp), 16, 0, 0)

// ---------- fused prep: weight casts + bias gather in one launch ----------
__global__ __launch_bounds__(256) void k_prep(const float* __restrict__ kw, const float* __restrict__ vw,
                                              const float* __restrict__ qw, const float* __restrict__ pw,
                                              const float* __restrict__ ab, const int* __restrict__ idxs, int noff,
                                              u16* __restrict__ kwb, u16* __restrict__ vwb,
                                              u16* __restrict__ qwb, u16* __restrict__ pwb,
                                              float* __restrict__ bxp) {
  int i = blockIdx.x * 256 + threadIdx.x;
  const int e1 = NH_KD * DIM;            // 49152
  const int e2 = e1 + DH * DIM;          // 245760
  const int e3 = e2 + NH_KD * DIM;       // 294912
  const int e4 = e3 + OUT_DIM * DH;      // 688128
  const int e5 = e4 + NUM_HEADS * N2 * 256;  // 888832
  if (i < e1) kwb[i] = f2bf(kw[i]);
  else if (i < e2) vwb[i - e1] = f2bf(vw[i - e1]);
  else if (i < e3) qwb[i - e2] = f2bf(qw[i - e2]);
  else if (i < e4) pwb[i - e3] = f2bf(pw[i - e3]);
  else if (i < e5) {
    int j = i - e4;
    int f = j & 15, c = (j >> 4) & 15;
    int m = (j >> 8) % N2, h = j / (N2 * 256);
    int n = f * 16 + c;
    bxp[j] = (n < NPOS) ? ab[h * noff + idxs[m * NPOS + n]] : 0.f;
  }
}

// ---------- x (f32 [b][384][196]) -> xbT (bf16 [b][196][384]) ----------
__global__ __launch_bounds__(256) void k_transpose(const float* __restrict__ x, u16* __restrict__ xt) {
  int b = blockIdx.y, c0 = blockIdx.x * 64;
  __shared__ u16 tile[64][196];
  int tid = threadIdx.x, wave = tid >> 6, lane = tid & 63;
  const float* xb = x + (size_t)b * DIM * NPOS;
  for (int r = wave; r < 64; r += 4) {
    const float* row = xb + (size_t)(c0 + r) * NPOS;
    tile[r][lane]       = f2bf(row[lane]);
    tile[r][lane + 64]  = f2bf(row[lane + 64]);
    tile[r][lane + 128] = f2bf(row[lane + 128]);
    if (lane < 4) tile[r][lane + 192] = f2bf(row[lane + 192]);
  }
  __syncthreads();
  u16* xtb = xt + (size_t)b * NPOS * DIM;
  for (int n = wave; n < NPOS; n += 4)
    xtb[(size_t)n * DIM + c0 + lane] = tile[lane][n];
}

// ---------- ql = dwconv_s2(x) + b + x[::2,::2] -> qlT, 8 channels/thread (G13) ----------
__global__ __launch_bounds__(256) void k_dwconv_q8(const u16* __restrict__ xt, const float* __restrict__ w,
                                                   const float* __restrict__ bias, u16* __restrict__ qlt) {
  int b = blockIdx.y;
  int lid = blockIdx.x * 256 + threadIdx.x;
  if (lid >= N2 * (DIM / 8)) return;
  int n2 = lid / (DIM / 8), c0 = (lid % (DIM / 8)) * 8;
  int r = n2 / RES2, s = n2 % RES2;
  const u16* xb = xt + (size_t)b * NPOS * DIM + c0;

  s16x8 xv[9];
#pragma unroll
  for (int dy = 0; dy < 3; dy++) {
    int ry = 2 * r - 1 + dy;
#pragma unroll
    for (int dx = 0; dx < 3; dx++) {
      int sx = 2 * s - 1 + dx;
      if (ry >= 0 && ry < RES && sx >= 0 && sx < RES)
        xv[dy * 3 + dx] = *(const s16x8*)(xb + (size_t)(ry * RES + sx) * DIM);
      else
        xv[dy * 3 + dx] = (s16x8){0, 0, 0, 0, 0, 0, 0, 0};
    }
  }
  s16x8 resid = *(const s16x8*)(xb + (size_t)(2 * r * RES + 2 * s) * DIM);
  s16x8 o;
#pragma unroll
  for (int e = 0; e < 8; e++) {
    const float* we = w + (size_t)(c0 + e) * 9;
    float a = bias[c0 + e] + bf2f((u16)resid[e]);
#pragma unroll
    for (int t = 0; t < 9; t++) a += we[t] * bf2f((u16)xv[t][e]);
    o[e] = (short)f2bf(a);
  }
  *(s16x8*)(qlt + ((size_t)b * N2 + n2) * DIM + c0) = o;
}

// ---------- flattened GEMM: C = A[M][K] x B[N][K]^T, both K-contiguous bf16 ----------
// 128x128 tile, BK=64 as two independent 8KB 32-K halves per operand (one barrier per
// 64-K: 8 GLD16/wave, then 2x16 MFMAs). Each half keeps the r7-verified layout:
// chunk = 1KB = 16 rows x 64B; wave w stages chunks w*2, w*2+1.
// Source pre-swizzle (m173/rule21): lane fetches global granule (l&3)^((l>>3)&3);
// frag reads un-swizzle with rg8 = ((l>>4)^((l>>1)&3))*8 -> conflict-free both sides.
// SPLN=0: out[m*ldc + n] (ch=n).  SPLN>0: out[(n/SPLN)*bstride + m*SPLN + n%SPLN] (ch=m).
template <int SPLN, bool F32OUT>
__global__ __launch_bounds__(256) void k_gemm_flat(
    const u16* __restrict__ A, const u16* __restrict__ B, void* __restrict__ C,
    const float* __restrict__ cb, const float* __restrict__ bns, const float* __restrict__ bnt,
    int K, int NMT, int ldc, long bstride) {
  __shared__ __align__(16) u16 a_lds[2 * 128 * 32];
  __shared__ __align__(16) u16 b_lds[2 * 128 * 32];
  int nwg = gridDim.x, bx = blockIdx.x;
  int wg = ((nwg & 7) == 0) ? ((bx & 7) * (nwg >> 3) + (bx >> 3)) : bx;  // XCD-bijective
  int mt = wg % NMT, nt = wg / NMT;                                      // m fastest: j-tile shared on-XCD
  int m0 = mt * 128, n0 = nt * 128;
  int tid = threadIdx.x, w = tid >> 6, l = tid & 63;

  int srow = l >> 2;
  int scol = ((l & 3) ^ ((l >> 3) & 3)) * 8;   // pre-swizzled source granule
  const u16* asrc[2]; const u16* bsrc[2];
#pragma unroll
  for (int c = 0; c < 2; c++) {
    int chunk = w * 2 + c;
    asrc[c] = A + (size_t)(m0 + chunk * 16 + srow) * K + scol;
    bsrc[c] = B + (size_t)(n0 + chunk * 16 + srow) * K + scol;
  }
  char* adst = (char*)a_lds + (w * 2) * 1024 + l * 16;
  char* bdst = (char*)b_lds + (w * 2) * 1024 + l * 16;

  f32x4 acc[4][4];
#pragma unroll
  for (int i = 0; i < 4; i++)
#pragma unroll
    for (int j = 0; j < 4; j++) acc[i][j] = (f32x4){0.f, 0.f, 0.f, 0.f};

  int wm = w >> 1, wn = w & 1;
  int rg8 = ((l >> 4) ^ ((l >> 1) & 3)) * 8;   // un-swizzling read granule
  int arow = wm * 64 + (l & 15);
  int brow = wn * 64 + (l & 15);

  for (int kk = 0; kk < K; kk += 64) {
#pragma unroll
    for (int c = 0; c < 2; c++) {
      GLD16(asrc[c] + kk,      adst + c * 1024);
      GLD16(asrc[c] + kk + 32, adst + 8192 + c * 1024);
      GLD16(bsrc[c] + kk,      bdst + c * 1024);
      GLD16(bsrc[c] + kk + 32, bdst + 8192 + c * 1024);
    }
    __syncthreads();                 // compiler drains vmcnt before barrier
#pragma unroll
    for (int hf = 0; hf < 2; hf++) {
      const u16* ah = a_lds + hf * (128 * 32);
      const u16* bh = b_lds + hf * (128 * 32);
      s16x8 af[4], bf[4];
#pragma unroll
      for (int i = 0; i < 4; i++) {
        af[i] = *(const s16x8*)(&ah[(arow + i * 16) * 32 + rg8]);
        bf[i] = *(const s16x8*)(&bh[(brow + i * 16) * 32 + rg8]);
      }
#pragma unroll
      for (int i = 0; i < 4; i++)
#pragma unroll
        for (int j = 0; j < 4; j++)
          acc[i][j] = __builtin_amdgcn_mfma_f32_16x16x32_bf16(af[i], bf[j], acc[i][j], 0, 0, 0);
    }
    __syncthreads();
  }

  int ncol = l & 15, mq = (l >> 4) * 4;
#pragma unroll
  for (int i = 0; i < 4; i++) {
#pragma unroll
    for (int j = 0; j < 4; j++) {
      int n = n0 + wn * 64 + j * 16 + ncol;
#pragma unroll
      for (int r = 0; r < 4; r++) {
        int m = m0 + wm * 64 + i * 16 + mq + r;
        int ch = SPLN ? m : n;
        float val = acc[i][j][r] * bns[ch] + (cb[ch] * bns[ch] + bnt[ch]);
        size_t o;
        if (SPLN) o = (size_t)(n / SPLN) * bstride + (size_t)m * SPLN + (n % SPLN);
        else      o = (size_t)m * ldc + n;
        if (F32OUT) ((float*)C)[o] = val;
        else        ((u16*)C)[o] = f2bf(val);
      }
    }
  }
}

// ---------- v_local = BN(dwconv_s2(v4) + b) -> vlT (bf16 [b][49][512]) ----------
__global__ __launch_bounds__(256) void k_dwconv_v(const u16* __restrict__ v4, const float* __restrict__ w,
    const float* __restrict__ bias, const float* __restrict__ bns, const float* __restrict__ bnt,
    u16* __restrict__ vlt) {
  int b = blockIdx.y, ct = blockIdx.x;
  __shared__ u16 tile[64][196];
  int tid = threadIdx.x, wave = tid >> 6, lane = tid & 63;
  const u16* vbp = v4 + ((size_t)b * DH + ct * 64) * NPOS;
  for (int r = wave; r < 64; r += 4) {
    const u16* row = vbp + (size_t)r * NPOS;
    tile[r][lane]       = row[lane];
    tile[r][lane + 64]  = row[lane + 64];
    tile[r][lane + 128] = row[lane + 128];
    if (lane < 4) tile[r][lane + 192] = row[lane + 192];
  }
  __syncthreads();
  for (int idx = tid; idx < 64 * N2; idx += 256) {
    int cl = idx & 63, n2 = idx >> 6;
    int ch = ct * 64 + cl;
    int r = n2 / RES2, s = n2 % RES2;
    float acc = bias[ch];
#pragma unroll
    for (int dy = 0; dy < 3; dy++) {
      int ry = 2 * r - 1 + dy;
      if (ry < 0 || ry >= RES) continue;
#pragma unroll
      for (int dx = 0; dx < 3; dx++) {
        int sx = 2 * s - 1 + dx;
        if (sx < 0 || sx >= RES) continue;
        acc += w[ch * 9 + dy * 3 + dx] * bf2f(tile[cl][ry * RES + sx]);
      }
    }
    vlt[((size_t)b * N2 + n2) * DH + ch] = f2bf(acc * bns[ch] + bnt[ch]);
  }
}

// ---------- MFMA attention per (b,h) ----------
// LDS 47.1 KB (3 blocks/CU): PV B-fragments read directly from v4 ([b][512][196]
// row-major = B-operand layout) as 2x8B loads; cols >=196 hit in-ws garbage x P=0.
// Iter-0 V frags issued right after QK^T (hide under softmax); 1-deep pipeline in PV.
// o_lds (f32, stride 68, 13.3 KB) overlaps dead q/k region (17.4 KB).
__global__ __launch_bounds__(256) void k_attn_mfma(const u16* __restrict__ qT, const u16* __restrict__ kT,
    const u16* __restrict__ v4, const float* __restrict__ bxp, const u16* __restrict__ vlT,
    u16* __restrict__ gT) {
  int h = blockIdx.x, b = blockIdx.y;
  __shared__ __align__(16) u16 smem[64 * 32 + 208 * 32 + 64 * 232];
  u16* q_lds = smem;                       // 64*32
  u16* k_lds = smem + 64 * 32;             // 208*32
  u16* p_lds = smem + 64 * 32 + 208 * 32;  // 64*232
  float* o_lds = (float*)smem;             // overlaps q_lds+k_lds
  int tid = threadIdx.x, w = tid >> 6, l = tid & 63;

  // --- stage q: row = tid>>2, part = tid&3 (parts 2,3 = K-pad zeros) ---
  {
    int row = tid >> 2, part = tid & 3;
    s16x8 val = (s16x8){0, 0, 0, 0, 0, 0, 0, 0};
    if (part < 2 && row < N2)
      val = *(const s16x8*)(qT + ((size_t)b * N2 + row) * NH_KD + h * 16 + part * 8);
    *(s16x8*)(&q_lds[row * 32 + part * 8]) = val;
  }
  // --- stage k ---
  for (int row = tid >> 2; row < 208; row += 64) {
    int part = tid & 3;
    s16x8 val = (s16x8){0, 0, 0, 0, 0, 0, 0, 0};
    if (part < 2 && row < NPOS)
      val = *(const s16x8*)(kT + ((size_t)b * NPOS + row) * NH_KD + h * 16 + part * 8);
    *(s16x8*)(&k_lds[row * 32 + part * 8]) = val;
  }
  // --- zero p_lds cols 208..223 (dwords 104..111) ---
  for (int idx = tid; idx < 64 * 8; idx += 256)
    ((uint*)&p_lds[(idx >> 3) * 232])[104 + (idx & 7)] = 0;

  // --- bias fragment loads (issued before barrier; independent of LDS) ---
  int mbase = w * 16 + (l >> 4) * 4;
  int ncol = l & 15;
  f32x4 bq[4][4];
#pragma unroll
  for (int r = 0; r < 4; r++) {
    int mm = mbase + r; if (mm > N2 - 1) mm = N2 - 1;
    const float* bb = bxp + (((size_t)h * N2 + mm) * 16 + ncol) * 16;
#pragma unroll
    for (int q = 0; q < 4; q++) bq[r][q] = *(const f32x4*)(bb + q * 4);
  }
  __syncthreads();

  // --- QK^T: wave w owns rows w*16..w*16+15; 13 col-frags ---
  f32x4 s[13];
  {
    s16x8 af = *(const s16x8*)(&q_lds[(w * 16 + (l & 15)) * 32 + (l >> 4) * 8]);
#pragma unroll
    for (int f = 0; f < 13; f++) {
      s16x8 bf = *(const s16x8*)(&k_lds[(f * 16 + (l & 15)) * 32 + (l >> 4) * 8]);
      s[f] = __builtin_amdgcn_mfma_f32_16x16x32_bf16(af, bf, (f32x4){0.f, 0.f, 0.f, 0.f}, 0, 0, 0);
    }
  }

  // --- V fragment geometry + iter-0 prefetch (hides under softmax) ---
  const u16* vbase = v4 + ((size_t)b * DH + h * DHEAD) * NPOS;
  int vd = l & 15, vq8 = (l >> 4) * 8;
  auto VLOAD = [&](int f, int kk) {
    const u16* p = vbase + (size_t)(f * 16 + vd) * NPOS + kk + vq8;
    s16x8 r;
    ((u32x2*)&r)[0] = *(const u32x2*)(p);        // 8B-aligned
    ((u32x2*)&r)[1] = *(const u32x2*)(p + 4);
    return r;
  };
  s16x8 vb0[4];
#pragma unroll
  for (int f = 0; f < 4; f++) vb0[f] = VLOAD(f, 0);

  // --- scale + bias + mask (C layout: col = l&15, row = (l>>4)*4 + reg) ---
#pragma unroll
  for (int f = 0; f < 13; f++) {
    int n = f * 16 + ncol;
#pragma unroll
    for (int r = 0; r < 4; r++) {
      int m = mbase + r;
      s[f][r] = (m < N2 && n < NPOS) ? s[f][r] * SCALE_Q + bq[r][f >> 2][f & 3] : -1e30f;
    }
  }
  // --- softmax: rows live in 16-lane groups -> shfl_xor 1,2,4,8 ---
#pragma unroll
  for (int r = 0; r < 4; r++) {
    float mx = s[0][r];
#pragma unroll
    for (int f = 1; f < 13; f++) mx = fmaxf(mx, s[f][r]);
    mx = fmaxf(mx, __shfl_xor(mx, 1)); mx = fmaxf(mx, __shfl_xor(mx, 2));
    mx = fmaxf(mx, __shfl_xor(mx, 4)); mx = fmaxf(mx, __shfl_xor(mx, 8));
    float sum = 0.f;
#pragma unroll
    for (int f = 0; f < 13; f++) { s[f][r] = __expf(s[f][r] - mx); sum += s[f][r]; }
    sum += __shfl_xor(sum, 1); sum += __shfl_xor(sum, 2);
    sum += __shfl_xor(sum, 4); sum += __shfl_xor(sum, 8);
    float inv = 1.f / sum;
#pragma unroll
    for (int f = 0; f < 13; f++) s[f][r] *= inv;
  }
  // --- P -> LDS (bf16), wave-local rows ---
#pragma unroll
  for (int f = 0; f < 13; f++) {
    int n = f * 16 + ncol;
#pragma unroll
    for (int r = 0; r < 4; r++)
      p_lds[(mbase + r) * 232 + n] = f2bf(s[f][r]);
  }
  __syncthreads();

  // --- PV: A = P rows (wave-local m-tile), B = V from GLOBAL, 1-deep pipeline, K = 224 ---
  f32x4 o[4];
#pragma unroll
  for (int f = 0; f < 4; f++) o[f] = (f32x4){0.f, 0.f, 0.f, 0.f};
#pragma unroll
  for (int t = 0; t < 7; t++) {
    int kk = t * 32;
    s16x8 vn[4];
    if (t < 6) {
#pragma unroll
      for (int f = 0; f < 4; f++) vn[f] = VLOAD(f, kk + 32);
    }
    s16x8 pa = *(const s16x8*)(&p_lds[(w * 16 + (l & 15)) * 232 + kk + (l >> 4) * 8]);
#pragma unroll
    for (int f = 0; f < 4; f++)
      o[f] = __builtin_amdgcn_mfma_f32_16x16x32_bf16(pa, vb0[f], o[f], 0, 0, 0);
    if (t < 6) {
#pragma unroll
      for (int f = 0; f < 4; f++) vb0[f] = vn[f];
    }
  }
  // --- o -> o_lds (overlaps dead q/k region; q/k reads all completed before prior barrier) ---
#pragma unroll
  for (int f = 0; f < 4; f++)
#pragma unroll
    for (int r = 0; r < 4; r++) {
      int m = mbase + r;
      if (m < N2) o_lds[m * 68 + f * 16 + ncol] = o[f][r];
    }
  __syncthreads();

  // --- cooperative epilogue: coalesced vlT add + gelu + gT store ---
  for (int idx = tid; idx < N2 * 16; idx += 256) {
    int row = idx >> 4, c4 = (idx & 15) << 2;
    f32x4 ov = *(const f32x4*)(&o_lds[row * 68 + c4]);
    size_t go = ((size_t)b * N2 + row) * DH + h * DHEAD + c4;
    s16x4 vv = *(const s16x4*)(vlT + go);
    s16x4 outv;
#pragma unroll
    for (int e = 0; e < 4; e++) {
      float xv = ov[e] + bf2f((u16)vv[e]);
      float g = 0.5f * xv * (1.f + erff(xv * 0.70710678118f));
      outv[e] = (short)f2bf(g);
    }
    *(s16x4*)(gT + go) = outv;
  }
}

extern "C" void kernel_launch(void* const* d_in, const int* in_sizes, int n_in,
                              void* d_out, int out_size, void* d_ws, size_t ws_size,
                              hipStream_t stream) {
  const float* x   = (const float*)d_in[0];
  const float* qlw = (const float*)d_in[1];
  const float* qlb = (const float*)d_in[2];
  const float* qpw = (const float*)d_in[3];
  const float* qpb = (const float*)d_in[4];
  const float* qbs = (const float*)d_in[5];
  const float* qbt = (const float*)d_in[6];
  const float* kw  = (const float*)d_in[7];
  const float* kb  = (const float*)d_in[8];
  const float* kbs = (const float*)d_in[9];
  const float* kbt = (const float*)d_in[10];
  const float* vw  = (const float*)d_in[11];
  const float* vb  = (const float*)d_in[12];
  const float* vbs = (const float*)d_in[13];
  const float* vbt = (const float*)d_in[14];
  const float* vlw = (const float*)d_in[15];
  const float* vlb = (const float*)d_in[16];
  const float* vls = (const float*)d_in[17];
  const float* vlt_in = (const float*)d_in[18];
  const float* pw  = (const float*)d_in[19];
  const float* pb  = (const float*)d_in[20];
  const float* pbs = (const float*)d_in[21];
  const float* pbt = (const float*)d_in[22];
  const float* ab  = (const float*)d_in[23];
  const int*   bidx = (const int*)d_in[24];
  int noff = in_sizes[23] / NUM_HEADS;

  char* ws = (char*)d_ws;
  size_t off = 0;
  auto alloc = [&](size_t bytes) { char* p = ws + off; off += (bytes + 255) & ~(size_t)255; return p; };
  u16* xbT = (u16*)alloc((size_t)BATCH * NPOS * DIM * 2);      // 77.1 MB (aliased by gT later)
  u16* kTm = (u16*)alloc((size_t)BATCH * NPOS * NH_KD * 2);    // 25.7 MB
  u16* qlT = (u16*)alloc((size_t)BATCH * N2 * DIM * 2);        // 19.3 MB
  u16* qTm = (u16*)alloc((size_t)BATCH * N2 * NH_KD * 2);      //  6.4 MB
  u16* v4m = (u16*)alloc((size_t)BATCH * DH * NPOS * 2);       // 102.8 MB
  u16* vlTm = (u16*)alloc((size_t)BATCH * N2 * DH * 2);        // 25.7 MB  (also absorbs attn's 56B OOB V reads)
  float* bxp = (float*)alloc((size_t)NUM_HEADS * N2 * 16 * 16 * 4);  // 0.8 MB
  u16* kwb = (u16*)alloc((size_t)NH_KD * DIM * 2);
  u16* vwb = (u16*)alloc((size_t)DH * DIM * 2);
  u16* qwb = (u16*)alloc((size_t)NH_KD * DIM * 2);
  u16* pwb = (u16*)alloc((size_t)OUT_DIM * DH * 2);
  u16* gTm = xbT;  // alias: all xbT readers complete before k_attn writes gT

  k_prep<<<(888832 + 255) / 256, 256, 0, stream>>>(kw, vw, qpw, pw, ab, bidx, noff,
                                                   kwb, vwb, qwb, pwb, bxp);

  k_transpose<<<dim3(6, BATCH), 256, 0, stream>>>(x, xbT);
  k_dwconv_q8<<<dim3((N2 * (DIM / 8) + 255) / 256, BATCH), 256, 0, stream>>>(xbT, qlw, qlb, qlT);

  // k: A=xbT[100352][384] (m=j), B=kwb[128][384] (n=ch) -> kTm[j][128]; 784 m-tiles x 1 n-tile
  k_gemm_flat<0, false><<<784, 256, 0, stream>>>(
      xbT, kwb, kTm, kb, kbs, kbt, DIM, 784, NH_KD, 0);
  // v: A=vwb[512][384] (m=ch), B=xbT (n=j) -> v4m[b][512][196]; 4 m-tiles x 784 n-tiles
  k_gemm_flat<NPOS, false><<<3136, 256, 0, stream>>>(
      vwb, xbT, v4m, vb, vbs, vbt, DIM, 4, 0, (long)DH * NPOS);
  // q: A=qlT[25088][384] (m=j), B=qwb (n=ch) -> qTm[j][128]; 196 m-tiles x 1 n-tile
  k_gemm_flat<0, false><<<196, 256, 0, stream>>>(
      qlT, qwb, qTm, qpb, qbs, qbt, DIM, 196, NH_KD, 0);

  k_dwconv_v<<<dim3(8, BATCH), 256, 0, stream>>>(v4m, vlw, vlb, vls, vlt_in, vlTm);
  k_attn_mfma<<<dim3(NUM_HEADS, BATCH), 256, 0, stream>>>(qTm, kTm, v4m, bxp, vlTm, gTm);

  // p: A=pwb[768][512] (m=ch), B=gTm[25088][512] (n=j) -> d_out[b][768][49] f32; 6 x 196
  k_gemm_flat<N2, true><<<1176, 256, 0, stream>>>(
      pwb, gTm, d_out, pb, pbs, pbt, DH, 6, 0, (long)OUT_DIM * N2);
}